// Round 2
// baseline (3273.491 us; speedup 1.0000x reference)
//
#include <hip/hip_runtime.h>
#include <math.h>

#define BB 2
#define CCH 8
#define BINS 1024
#define WW 512
#define HEADS 16
#define HD 64
#define ROTD 32
#define EXPF 4
#define NXE 8388608L   // B*C*BINS*W

// ---------------- batched GEMM: C[z] = A[z%aMod] @ B[z] (+R[z]) ----------------
// A row-major [M][K], B [K][N], C [M][N]
template<bool HASRES>
__global__ __launch_bounds__(256)
void gemm_k(const float* __restrict__ A, long sA, int aMod, int ldA,
            const float* __restrict__ B, long sB, int ldB,
            float* __restrict__ C, long sC, int ldC,
            const float* __restrict__ R, long sR,
            int M, int N, int K)
{
    __shared__ __attribute__((aligned(16))) float As[16][68];
    __shared__ __attribute__((aligned(16))) float Bs[16][68];
    const int z = blockIdx.z;
    const float* Ab = A + (long)(z % aMod) * sA;
    const float* Bb = B + (long)z * sB;
    float* Cb = C + (long)z * sC;
    const int m0 = blockIdx.y * 64, n0 = blockIdx.x * 64;
    const int tid = threadIdx.x;
    const int tx = tid & 15, ty = tid >> 4;
    float acc[4][4] = {};

    for (int k0 = 0; k0 < K; k0 += 16) {
        #pragma unroll
        for (int t = 0; t < 4; ++t) {
            int idx = tid + t * 256;
            { int k = idx & 15, m = idx >> 4;
              As[k][m] = Ab[(long)(m0 + m) * ldA + (k0 + k)]; }
            { int n = idx & 63, k = idx >> 6;
              Bs[k][n] = Bb[(long)(k0 + k) * ldB + (n0 + n)]; }
        }
        __syncthreads();
        #pragma unroll
        for (int kk = 0; kk < 16; ++kk) {
            float4 a4 = *(const float4*)&As[kk][ty * 4];
            float4 b4 = *(const float4*)&Bs[kk][tx * 4];
            float av[4] = {a4.x, a4.y, a4.z, a4.w};
            float bv[4] = {b4.x, b4.y, b4.z, b4.w};
            #pragma unroll
            for (int i = 0; i < 4; ++i)
                #pragma unroll
                for (int j = 0; j < 4; ++j)
                    acc[i][j] = fmaf(av[i], bv[j], acc[i][j]);
        }
        __syncthreads();
    }

    #pragma unroll
    for (int i = 0; i < 4; ++i) {
        int m = m0 + ty * 4 + i;
        #pragma unroll
        for (int j = 0; j < 4; ++j) {
            int n = n0 + tx * 4 + j;
            float v = acc[i][j];
            if (HASRES) v += R[(long)z * sR + (long)m * ldC + n];
            Cb[(long)m * ldC + n] = v;
        }
    }
}

// ---------------- frame norm over BINS axis ----------------
__global__ __launch_bounds__(256)
void norm_k(const float* __restrict__ X, const float* __restrict__ wgt,
            const float* __restrict__ bia, float* __restrict__ Y)
{
    __shared__ float red0[4][64];
    __shared__ float red1[4][64];
    __shared__ float ms[64], is[64];
    const int blk = blockIdx.x;
    const int bc = blk / (WW / 64);
    const int w0 = (blk % (WW / 64)) * 64;
    const int tx = threadIdx.x & 63, ty = threadIdx.x >> 6;
    const float* Xb = X + (long)bc * BINS * WW + w0;
    float s = 0.f, s2 = 0.f;
    for (int f = ty; f < BINS; f += 4) {
        float v = Xb[(long)f * WW + tx];
        s += v; s2 += v * v;
    }
    red0[ty][tx] = s; red1[ty][tx] = s2;
    __syncthreads();
    if (ty == 0) {
        float ss = red0[0][tx] + red0[1][tx] + red0[2][tx] + red0[3][tx];
        float qq = red1[0][tx] + red1[1][tx] + red1[2][tx] + red1[3][tx];
        float m = ss * (1.f / BINS);
        float var = qq * (1.f / BINS) - m * m;
        ms[tx] = m; is[tx] = rsqrtf(var + 1e-5f);
    }
    __syncthreads();
    float m = ms[tx], inv = is[tx];
    float* Yb = Y + (long)bc * BINS * WW + w0;
    for (int f = ty; f < BINS; f += 4) {
        float v = Xb[(long)f * WW + tx];
        Yb[(long)f * WW + tx] = (v - m) * inv * wgt[f] + bia[f];
    }
}

// ---------------- RoPE tables ----------------
__global__ void rope_tab_k(const float* __restrict__ freqs,
                           float* __restrict__ cosT, float* __restrict__ sinT)
{
    int idx = blockIdx.x * 256 + threadIdx.x;   // W*16 = 8192
    if (idx >= WW * 16) return;
    int w = idx >> 4, i = idx & 15;
    float ang = (float)w * freqs[i];
    cosT[idx] = cosf(ang);
    sinT[idx] = sinf(ang);
}

// ---------------- RoPE rotate ----------------
__global__ __launch_bounds__(256)
void rope_k(const float* __restrict__ Yin, const float* __restrict__ cosT,
            const float* __restrict__ sinT, float* __restrict__ Rout)
{
    long idx = (long)blockIdx.x * 256 + threadIdx.x;
    if (idx >= NXE) return;
    int w = (int)(idx & (WW - 1));
    int g = (int)((idx >> 9) & (BINS - 1));
    int d = g & 63;
    float v = Yin[idx];
    float r;
    if (d >= ROTD) {
        r = v;
    } else {
        int i = d >> 1;
        float c = cosT[w * 16 + i], s = sinT[w * 16 + i];
        if ((d & 1) == 0) { float p = Yin[idx + WW]; r = v * c - p * s; }
        else             { float p = Yin[idx - WW]; r = v * c + p * s; }
    }
    Rout[idx] = r;
}

// ---------------- fused flash attention ----------------
// rot: [z][d][w] (q = k), v: [z][d][w], o: [z][d][w];  z = bc*16 + h
__global__ __launch_bounds__(256)
void attn_k(const float* __restrict__ rot, const float* __restrict__ vv,
            float* __restrict__ o)
{
    __shared__ __attribute__((aligned(16))) float Qs[64][68];
    __shared__ __attribute__((aligned(16))) float Ks[64][68];
    __shared__ __attribute__((aligned(16))) float Vs[64][68];
    __shared__ __attribute__((aligned(16))) float Ps[64][68];
    const int z = blockIdx.y;
    const long base = (long)z * HD * WW;
    const int wq0 = blockIdx.x * 64;
    const int tid = threadIdx.x;
    const int tx = tid & 15, ty = tid >> 4;

    #pragma unroll
    for (int t = 0; t < 16; ++t) {
        int idx = tid + t * 256;
        int col = idx & 63, d = idx >> 6;
        Qs[d][col] = rot[base + (long)d * WW + wq0 + col] * (1.f / 32.f);
    }
    __syncthreads();

    float oacc[4][4] = {};
    float mrow[4] = {-INFINITY, -INFINITY, -INFINITY, -INFINITY};
    float lrow[4] = {0.f, 0.f, 0.f, 0.f};

    for (int u0 = 0; u0 < WW; u0 += 64) {
        #pragma unroll
        for (int t = 0; t < 16; ++t) {
            int idx = tid + t * 256;
            int cu = idx & 63, d = idx >> 6;
            float kvK = rot[base + (long)d * WW + u0 + cu];
            float kvV = vv [base + (long)d * WW + u0 + cu];
            Ks[d][cu] = kvK;
            Vs[cu][d] = kvV;
        }
        __syncthreads();

        float s[4][4] = {};
        #pragma unroll
        for (int kk = 0; kk < 64; ++kk) {
            float4 a4 = *(const float4*)&Qs[kk][ty * 4];
            float4 b4 = *(const float4*)&Ks[kk][tx * 4];
            float av[4] = {a4.x, a4.y, a4.z, a4.w};
            float bv[4] = {b4.x, b4.y, b4.z, b4.w};
            #pragma unroll
            for (int i = 0; i < 4; ++i)
                #pragma unroll
                for (int j = 0; j < 4; ++j)
                    s[i][j] = fmaf(av[i], bv[j], s[i][j]);
        }

        #pragma unroll
        for (int i = 0; i < 4; ++i) {
            float mx = fmaxf(fmaxf(s[i][0], s[i][1]), fmaxf(s[i][2], s[i][3]));
            mx = fmaxf(mx, __shfl_xor(mx, 1));
            mx = fmaxf(mx, __shfl_xor(mx, 2));
            mx = fmaxf(mx, __shfl_xor(mx, 4));
            mx = fmaxf(mx, __shfl_xor(mx, 8));
            float mnew = fmaxf(mrow[i], mx);
            float al = expf(mrow[i] - mnew);
            float rs = 0.f;
            #pragma unroll
            for (int j = 0; j < 4; ++j) { s[i][j] = expf(s[i][j] - mnew); rs += s[i][j]; }
            rs += __shfl_xor(rs, 1);
            rs += __shfl_xor(rs, 2);
            rs += __shfl_xor(rs, 4);
            rs += __shfl_xor(rs, 8);
            lrow[i] = lrow[i] * al + rs;
            mrow[i] = mnew;
            #pragma unroll
            for (int j = 0; j < 4; ++j) oacc[i][j] *= al;
        }

        #pragma unroll
        for (int i = 0; i < 4; ++i)
            #pragma unroll
            for (int j = 0; j < 4; ++j)
                Ps[tx * 4 + j][ty * 4 + i] = s[i][j];
        __syncthreads();

        #pragma unroll
        for (int kk = 0; kk < 64; ++kk) {
            float4 a4 = *(const float4*)&Ps[kk][ty * 4];
            float4 b4 = *(const float4*)&Vs[kk][tx * 4];
            float av[4] = {a4.x, a4.y, a4.z, a4.w};
            float bv[4] = {b4.x, b4.y, b4.z, b4.w};
            #pragma unroll
            for (int i = 0; i < 4; ++i)
                #pragma unroll
                for (int j = 0; j < 4; ++j)
                    oacc[i][j] = fmaf(av[i], bv[j], oacc[i][j]);
        }
        __syncthreads();
    }

    #pragma unroll
    for (int i = 0; i < 4; ++i) {
        float inv = 1.f / lrow[i];
        #pragma unroll
        for (int j = 0; j < 4; ++j)
            o[base + (long)(tx * 4 + j) * WW + wq0 + ty * 4 + i] = oacc[i][j] * inv;
    }
}

// ---------------- exact GELU ----------------
__global__ __launch_bounds__(256)
void gelu_k(float* __restrict__ Hm, long n)
{
    long idx = (long)blockIdx.x * 256 + threadIdx.x;
    if (idx >= n) return;
    float x = Hm[idx];
    Hm[idx] = 0.5f * x * (1.f + erff(x * 0.70710678118654752f));
}

extern "C" void kernel_launch(void* const* d_in, const int* in_sizes, int n_in,
                              void* d_out, int out_size, void* d_ws, size_t ws_size,
                              hipStream_t stream)
{
    const float* x    = (const float*)d_in[0];
    const float* n1w  = (const float*)d_in[1];
    const float* n1b  = (const float*)d_in[2];
    const float* freqs= (const float*)d_in[3];
    const float* qw   = (const float*)d_in[4];
    const float* ow   = (const float*)d_in[5];
    const float* n2w  = (const float*)d_in[6];
    const float* n2b  = (const float*)d_in[7];
    const float* l1w  = (const float*)d_in[8];
    const float* l2w  = (const float*)d_in[9];
    float* out = (float*)d_out;
    float* ws  = (float*)d_ws;

    float* A  = ws;              // norm1 -> rot -> norm2 out
    float* Bf = ws + NXE;        // y (q/k/v pre-rope)   [later h1 part]
    float* Cf = ws + 2 * NXE;    // attn out             [later h1 part]
    float* h1 = ws + NXE;        // 4*NXE MLP hidden
    float* cosT = ws + 5 * NXE;  // 8192
    float* sinT = cosT + WW * 16;

    rope_tab_k<<<32, 256, 0, stream>>>(freqs, cosT, sinT);

    // norm1: x -> A
    norm_k<<<BB * CCH * WW / 64, 256, 0, stream>>>(x, n1w, n1b, A);

    // qproj: Bf = q_w[c] @ A
    gemm_k<false><<<dim3(8, 16, 16), 256, 0, stream>>>(
        qw, (long)BINS * BINS, CCH, BINS,
        A,  (long)BINS * WW, WW,
        Bf, (long)BINS * WW, WW,
        nullptr, 0, BINS, WW, BINS);

    // rope: Bf -> A
    rope_k<<<NXE / 256, 256, 0, stream>>>(Bf, cosT, sinT, A);

    // fused attention: q=k=A, v=Bf -> Cf
    attn_k<<<dim3(8, 256), 256, 0, stream>>>(A, Bf, Cf);

    // outproj + residual: out = x + out_w[c] @ Cf
    gemm_k<true><<<dim3(8, 16, 16), 256, 0, stream>>>(
        ow, (long)BINS * BINS, CCH, BINS,
        Cf, (long)BINS * WW, WW,
        out,(long)BINS * WW, WW,
        x,  (long)BINS * WW, BINS, WW, BINS);

    // norm2: out -> A
    norm_k<<<BB * CCH * WW / 64, 256, 0, stream>>>(out, n2w, n2b, A);

    // lin1: h1 = l1w[c] @ A
    gemm_k<false><<<dim3(8, 64, 16), 256, 0, stream>>>(
        l1w, (long)BINS * EXPF * BINS, CCH, BINS,
        A,   (long)BINS * WW, WW,
        h1,  (long)BINS * EXPF * WW, WW,
        nullptr, 0, BINS * EXPF, WW, BINS);

    // gelu in-place
    gelu_k<<<(4L * NXE) / 256, 256, 0, stream>>>(h1, 4L * NXE);

    // lin2 + residual (in-place on out): out = out + l2w[c] @ h1
    gemm_k<true><<<dim3(8, 16, 16), 256, 0, stream>>>(
        l2w, (long)BINS * BINS * EXPF, CCH, BINS * EXPF,
        h1,  (long)BINS * EXPF * WW, WW,
        out, (long)BINS * WW, WW,
        out, (long)BINS * WW, BINS, WW, BINS * EXPF);
}

// Round 3
// 996.048 us; speedup vs baseline: 3.2865x; 3.2865x over previous
//
#include <hip/hip_runtime.h>
#include <math.h>

#define BB 2
#define CCH 8
#define BINS 1024
#define WW 512
#define HEADS 16
#define HD 64
#define ROTD 32
#define EXPF 4
#define NXE 8388608L   // B*C*BINS*W

typedef unsigned short ushortT;
typedef short bf16x8 __attribute__((ext_vector_type(8)));
typedef float f32x4 __attribute__((ext_vector_type(4)));

__device__ __forceinline__ ushortT f2bf(float f) {
    unsigned int u = __float_as_uint(f);
    u = (u + 0x7FFF + ((u >> 16) & 1)) >> 16;
    return (ushortT)u;
}

__device__ __forceinline__ float geluf(float x) {
    return 0.5f * x * (1.f + erff(x * 0.70710678118654752f));
}

__device__ __forceinline__ void gl_lds16(const ushortT* g, ushortT* l) {
    __builtin_amdgcn_global_load_lds(
        (const __attribute__((address_space(1))) unsigned int*)g,
        (__attribute__((address_space(3))) unsigned int*)l, 16, 0, 0);
}

// ---------------- weight cast f32 -> bf16 ----------------
__global__ __launch_bounds__(256)
void wcast_k(const float* __restrict__ s, ushortT* __restrict__ d, long n)
{
    long i = ((long)blockIdx.x * 256 + threadIdx.x) * 8;
    if (i >= n) return;
    float4 a = *(const float4*)&s[i];
    float4 b = *(const float4*)&s[i + 4];
    union { ushortT h[8]; uint4 v; } r;
    r.h[0] = f2bf(a.x); r.h[1] = f2bf(a.y); r.h[2] = f2bf(a.z); r.h[3] = f2bf(a.w);
    r.h[4] = f2bf(b.x); r.h[5] = f2bf(b.y); r.h[6] = f2bf(b.z); r.h[7] = f2bf(b.w);
    *(uint4*)&d[i] = r.v;
}

// ---------------- frame norm over BINS, transposed bf16 out [w][f] ----------------
__global__ __launch_bounds__(256)
void normT_k(const float* __restrict__ X, const float* __restrict__ wgt,
             const float* __restrict__ bia, ushortT* __restrict__ YT)
{
    __shared__ float red0[4][64], red1[4][64];
    __shared__ float ms[64], is[64];
    __shared__ float T[64][65];
    const int blk = blockIdx.x;
    const int bc = blk / (WW / 64);
    const int w0 = (blk % (WW / 64)) * 64;
    const int tx = threadIdx.x & 63, ty = threadIdx.x >> 6;
    const float* Xb = X + (long)bc * BINS * WW + w0;
    float s = 0.f, s2 = 0.f;
    for (int f = ty; f < BINS; f += 4) {
        float v = Xb[(long)f * WW + tx];
        s += v; s2 += v * v;
    }
    red0[ty][tx] = s; red1[ty][tx] = s2;
    __syncthreads();
    if (ty == 0) {
        float ss = red0[0][tx] + red0[1][tx] + red0[2][tx] + red0[3][tx];
        float qq = red1[0][tx] + red1[1][tx] + red1[2][tx] + red1[3][tx];
        float m = ss * (1.f / BINS);
        float var = qq * (1.f / BINS) - m * m;
        ms[tx] = m; is[tx] = rsqrtf(var + 1e-5f);
    }
    __syncthreads();
    ushortT* Yb = YT + (long)bc * WW * BINS;
    for (int f0 = 0; f0 < BINS; f0 += 64) {
        #pragma unroll
        for (int fy = 0; fy < 64; fy += 4)
            T[fy + ty][tx] = Xb[(long)(f0 + fy + ty) * WW + tx];
        __syncthreads();
        float wv = wgt[f0 + tx], bv = bia[f0 + tx];
        #pragma unroll
        for (int wy = 0; wy < 64; wy += 4) {
            int w = wy + ty;
            float v = (T[tx][w] - ms[w]) * is[w] * wv + bv;
            Yb[(long)(w0 + w) * BINS + f0 + tx] = f2bf(v);
        }
        __syncthreads();
    }
}

// ---------------- RoPE tables ----------------
__global__ void rope_tab_k(const float* __restrict__ freqs,
                           float* __restrict__ cosT, float* __restrict__ sinT)
{
    int idx = blockIdx.x * 256 + threadIdx.x;   // W*16 = 8192
    if (idx >= WW * 16) return;
    int w = idx >> 4, i = idx & 15;
    float ang = (float)w * freqs[i];
    cosT[idx] = cosf(ang);
    sinT[idx] = sinf(ang);
}

// ---------------- RoPE rotate (fp32 [g][w]) ----------------
__global__ __launch_bounds__(256)
void rope_k(const float* __restrict__ Yin, const float* __restrict__ cosT,
            const float* __restrict__ sinT, float* __restrict__ Rout)
{
    long idx = (long)blockIdx.x * 256 + threadIdx.x;
    if (idx >= NXE) return;
    int w = (int)(idx & (WW - 1));
    int g = (int)((idx >> 9) & (BINS - 1));
    int d = g & 63;
    float v = Yin[idx];
    float r;
    if (d >= ROTD) {
        r = v;
    } else {
        int i = d >> 1;
        float c = cosT[w * 16 + i], s = sinT[w * 16 + i];
        if ((d & 1) == 0) { float p = Yin[idx + WW]; r = v * c - p * s; }
        else             { float p = Yin[idx - WW]; r = v * c + p * s; }
    }
    Rout[idx] = r;
}

// ---------------- fused flash attention, bf16-transposed output [w][g] ----------------
__global__ __launch_bounds__(256)
void attn_k(const float* __restrict__ rot, const float* __restrict__ vv,
            ushortT* __restrict__ oT)
{
    __shared__ __attribute__((aligned(16))) float Qs[64][68];
    __shared__ __attribute__((aligned(16))) float Ks[64][68];
    __shared__ __attribute__((aligned(16))) float Vs[64][68];
    __shared__ __attribute__((aligned(16))) float Ps[64][68];
    const int z = blockIdx.y;
    const int bc = z >> 4, hh = z & 15;
    const long base = (long)z * HD * WW;
    const int wq0 = blockIdx.x * 64;
    const int tid = threadIdx.x;
    const int tx = tid & 15, ty = tid >> 4;

    #pragma unroll
    for (int t = 0; t < 16; ++t) {
        int idx = tid + t * 256;
        int col = idx & 63, d = idx >> 6;
        Qs[d][col] = rot[base + (long)d * WW + wq0 + col] * (1.f / 32.f);
    }
    __syncthreads();

    float oacc[4][4] = {};
    float mrow[4] = {-INFINITY, -INFINITY, -INFINITY, -INFINITY};
    float lrow[4] = {0.f, 0.f, 0.f, 0.f};

    for (int u0 = 0; u0 < WW; u0 += 64) {
        #pragma unroll
        for (int t = 0; t < 16; ++t) {
            int idx = tid + t * 256;
            int cu = idx & 63, d = idx >> 6;
            Ks[d][cu] = rot[base + (long)d * WW + u0 + cu];
            Vs[cu][d] = vv [base + (long)d * WW + u0 + cu];
        }
        __syncthreads();

        float s[4][4] = {};
        #pragma unroll
        for (int kk = 0; kk < 64; ++kk) {
            float4 a4 = *(const float4*)&Qs[kk][ty * 4];
            float4 b4 = *(const float4*)&Ks[kk][tx * 4];
            float av[4] = {a4.x, a4.y, a4.z, a4.w};
            float bv[4] = {b4.x, b4.y, b4.z, b4.w};
            #pragma unroll
            for (int i = 0; i < 4; ++i)
                #pragma unroll
                for (int j = 0; j < 4; ++j)
                    s[i][j] = fmaf(av[i], bv[j], s[i][j]);
        }

        #pragma unroll
        for (int i = 0; i < 4; ++i) {
            float mx = fmaxf(fmaxf(s[i][0], s[i][1]), fmaxf(s[i][2], s[i][3]));
            mx = fmaxf(mx, __shfl_xor(mx, 1));
            mx = fmaxf(mx, __shfl_xor(mx, 2));
            mx = fmaxf(mx, __shfl_xor(mx, 4));
            mx = fmaxf(mx, __shfl_xor(mx, 8));
            float mnew = fmaxf(mrow[i], mx);
            float al = expf(mrow[i] - mnew);
            float rs = 0.f;
            #pragma unroll
            for (int j = 0; j < 4; ++j) { s[i][j] = expf(s[i][j] - mnew); rs += s[i][j]; }
            rs += __shfl_xor(rs, 1);
            rs += __shfl_xor(rs, 2);
            rs += __shfl_xor(rs, 4);
            rs += __shfl_xor(rs, 8);
            lrow[i] = lrow[i] * al + rs;
            mrow[i] = mnew;
            #pragma unroll
            for (int j = 0; j < 4; ++j) oacc[i][j] *= al;
        }

        #pragma unroll
        for (int i = 0; i < 4; ++i)
            #pragma unroll
            for (int j = 0; j < 4; ++j)
                Ps[tx * 4 + j][ty * 4 + i] = s[i][j];
        __syncthreads();

        #pragma unroll
        for (int kk = 0; kk < 64; ++kk) {
            float4 a4 = *(const float4*)&Ps[kk][ty * 4];
            float4 b4 = *(const float4*)&Vs[kk][tx * 4];
            float av[4] = {a4.x, a4.y, a4.z, a4.w};
            float bv[4] = {b4.x, b4.y, b4.z, b4.w};
            #pragma unroll
            for (int i = 0; i < 4; ++i)
                #pragma unroll
                for (int j = 0; j < 4; ++j)
                    oacc[i][j] = fmaf(av[i], bv[j], oacc[i][j]);
        }
        __syncthreads();
    }

    // write O^T as bf16: oT[bc][w][hh*64+d]
    #pragma unroll
    for (int i = 0; i < 4; ++i) {
        float inv = 1.f / lrow[i];
        #pragma unroll
        for (int j = 0; j < 4; ++j)
            Ps[ty * 4 + i][tx * 4 + j] = oacc[i][j] * inv;
    }
    __syncthreads();
    int wloc = tid >> 2, cc = tid & 3;
    union { ushortT h[16]; uint4 v[2]; } r;
    #pragma unroll
    for (int e = 0; e < 16; ++e) r.h[e] = f2bf(Ps[wloc][cc * 16 + e]);
    ushortT* dst = oT + ((long)bc * WW + wq0 + wloc) * BINS + hh * 64 + cc * 16;
    *(uint4*)dst = r.v[0];
    *(uint4*)(dst + 8) = r.v[1];
}

// ---------------- bf16 MFMA GEMM ----------------
// C[z][M][N] = A[z%aMod][M][K] @ B[z][N][K]^T  (both operands k-contiguous bf16)
// TRANSOUT: write bf16 C^T [N][M] instead (with optional GELU). Else fp32 [M][N] (+R).
template<bool HASRES, bool GELUF, bool TRANSOUT>
__global__ __launch_bounds__(256)
void mgemm_k(const ushortT* __restrict__ A, long sA, int aMod,
             const ushortT* __restrict__ B, long sB,
             void* __restrict__ Cp, long sC,
             const float* __restrict__ R, long sR,
             int M, int N, int K)
{
    __shared__ ushortT smem[(128 + 128) * 64];   // As 16KB | Bs 16KB
    ushortT* As = smem;
    ushortT* Bs = smem + 128 * 64;
    const int z = blockIdx.z;
    const ushortT* Ab = A + (long)(z % aMod) * sA + (long)blockIdx.y * 128 * K;
    const ushortT* Bb = B + (long)z * sB + (long)blockIdx.x * 128 * K;
    const int tid = threadIdx.x;
    const int wv = tid >> 6, l = tid & 63;
    const int lrow = l & 15, lk = l >> 4;
    const int mb = (wv >> 1) * 64, nb = (wv & 1) * 64;
    f32x4 acc[4][4] = {};

    for (int k0 = 0; k0 < K; k0 += 64) {
        #pragma unroll
        for (int t = 0; t < 4; ++t) {
            int r0 = wv * 32 + t * 8;
            int row = r0 + (l >> 3);
            int gs = (l & 7) ^ (row & 7);
            gl_lds16(Ab + (long)row * K + k0 + gs * 8, As + r0 * 64);
            gl_lds16(Bb + (long)row * K + k0 + gs * 8, Bs + r0 * 64);
        }
        __syncthreads();
        #pragma unroll
        for (int ko = 0; ko < 2; ++ko) {
            bf16x8 af[4], bg[4];
            #pragma unroll
            for (int i = 0; i < 4; ++i) {
                int ra = mb + i * 16 + lrow;
                af[i] = *(const bf16x8*)&As[ra * 64 + ((lk + ko * 4) ^ (ra & 7)) * 8];
                int rb = nb + i * 16 + lrow;
                bg[i] = *(const bf16x8*)&Bs[rb * 64 + ((lk + ko * 4) ^ (rb & 7)) * 8];
            }
            #pragma unroll
            for (int i = 0; i < 4; ++i)
                #pragma unroll
                for (int j = 0; j < 4; ++j)
                    acc[i][j] = __builtin_amdgcn_mfma_f32_16x16x32_bf16(
                        af[i], bg[j], acc[i][j], 0, 0, 0);
        }
        __syncthreads();
    }

    const int m0g = blockIdx.y * 128 + mb, n0g = blockIdx.x * 128 + nb;
    if (!TRANSOUT) {
        float* Cf = (float*)Cp + (long)z * sC;
        #pragma unroll
        for (int i = 0; i < 4; ++i)
            #pragma unroll
            for (int j = 0; j < 4; ++j)
                #pragma unroll
                for (int rg = 0; rg < 4; ++rg) {
                    long m = m0g + i * 16 + lk * 4 + rg;
                    long n = n0g + j * 16 + lrow;
                    float v = acc[i][j][rg];
                    if (GELUF) v = geluf(v);
                    if (HASRES) v += R[(long)z * sR + m * N + n];
                    Cf[m * N + n] = v;
                }
    } else {
        ushortT* Ts = smem + wv * 4096;   // 64x64 bf16 per wave
        #pragma unroll
        for (int i = 0; i < 4; ++i)
            #pragma unroll
            for (int j = 0; j < 4; ++j)
                #pragma unroll
                for (int rg = 0; rg < 4; ++rg) {
                    int ml = i * 16 + lk * 4 + rg;
                    int nl = j * 16 + lrow;
                    float v = acc[i][j][rg];
                    if (GELUF) v = geluf(v);
                    Ts[nl * 64 + (((ml >> 3) ^ (nl & 7)) << 3) + (ml & 7)] = f2bf(v);
                }
        __syncthreads();
        ushortT* CT = (ushortT*)Cp + (long)z * sC;
        #pragma unroll
        for (int p = 0; p < 8; ++p) {
            int nl = p * 8 + (l >> 3), mc = l & 7;
            uint4 d = *(const uint4*)&Ts[nl * 64 + ((mc ^ (nl & 7)) << 3)];
            *(uint4*)&CT[(long)(n0g + nl) * M + m0g + mc * 8] = d;
        }
    }
}

extern "C" void kernel_launch(void* const* d_in, const int* in_sizes, int n_in,
                              void* d_out, int out_size, void* d_ws, size_t ws_size,
                              hipStream_t stream)
{
    const float* x    = (const float*)d_in[0];
    const float* n1w  = (const float*)d_in[1];
    const float* n1b  = (const float*)d_in[2];
    const float* freqs= (const float*)d_in[3];
    const float* qw   = (const float*)d_in[4];
    const float* ow   = (const float*)d_in[5];
    const float* n2w  = (const float*)d_in[6];
    const float* n2b  = (const float*)d_in[7];
    const float* l1w  = (const float*)d_in[8];
    const float* l2w  = (const float*)d_in[9];
    float* out = (float*)d_out;
    char* wsb  = (char*)d_ws;
    const long MB = 1L << 20;

    // workspace map (max live 160MB + tables):
    ushortT* qwB  = (ushortT*)(wsb + 0 * MB);     // 16MB, dead after qproj
    ushortT* owB  = (ushortT*)(wsb + 16 * MB);    // 16MB, dead after outproj
    ushortT* znT  = (ushortT*)(wsb + 32 * MB);    // 16MB, dead after qproj
    ushortT* l1wB = (ushortT*)(wsb + 0 * MB);     // 64MB, cast after outproj
    ushortT* l2wB = (ushortT*)(wsb + 0 * MB);     // 64MB, cast after lin1
    float*   y    = (float*)  (wsb + 64 * MB);    // 32MB, dead after attn
    ushortT* zn2T = (ushortT*)(wsb + 64 * MB);    // 16MB, after y dead
    float*   rot  = (float*)  (wsb + 96 * MB);    // 32MB, dead after attn
    ushortT* CfT  = (ushortT*)(wsb + 32 * MB);    // 16MB, attn out (znT slot)
    ushortT* h1T  = (ushortT*)(wsb + 96 * MB);    // 64MB (rot slot)
    float*   cosT = (float*)  (wsb + 160 * MB);
    float*   sinT = cosT + WW * 16;

    rope_tab_k<<<32, 256, 0, stream>>>(freqs, cosT, sinT);

    wcast_k<<<4096, 256, 0, stream>>>(qw, qwB, 8L * BINS * BINS);
    wcast_k<<<4096, 256, 0, stream>>>(ow, owB, 8L * BINS * BINS);

    // norm1: x -> znT (bf16 [w][f])
    normT_k<<<BB * CCH * (WW / 64), 256, 0, stream>>>(x, n1w, n1b, znT);

    // qproj: y = qwB[c] @ znT^T   -> fp32 [g][w]
    mgemm_k<false, false, false><<<dim3(4, 8, 16), 256, 0, stream>>>(
        qwB, (long)BINS * BINS, CCH,
        znT, (long)WW * BINS,
        y,   (long)BINS * WW,
        nullptr, 0, BINS, WW, BINS);

    // rope: y -> rot (fp32)
    rope_k<<<NXE / 256, 256, 0, stream>>>(y, cosT, sinT, rot);

    // attention: q=k=rot, v=y -> CfT (bf16 [w][g])
    attn_k<<<dim3(8, 256), 256, 0, stream>>>(rot, y, CfT);

    // outproj + residual: out = x + owB[c] @ CfT^T
    mgemm_k<true, false, false><<<dim3(4, 8, 16), 256, 0, stream>>>(
        owB, (long)BINS * BINS, CCH,
        CfT, (long)WW * BINS,
        out, (long)BINS * WW,
        x,   (long)BINS * WW, BINS, WW, BINS);

    // cast l1w now (overwrites qwB/owB/znT region)
    wcast_k<<<16384, 256, 0, stream>>>(l1w, l1wB, 8L * BINS * EXPF * BINS);

    // norm2: out -> zn2T (bf16 [w][f], overwrites y)
    normT_k<<<BB * CCH * (WW / 64), 256, 0, stream>>>(out, n2w, n2b, zn2T);

    // lin1 + GELU, transposed bf16 out: h1T [w][4096]
    mgemm_k<false, true, true><<<dim3(4, 32, 16), 256, 0, stream>>>(
        l1wB, (long)BINS * EXPF * BINS, CCH,
        zn2T, (long)WW * BINS,
        h1T,  (long)WW * BINS * EXPF,
        nullptr, 0, BINS * EXPF, WW, BINS);

    // cast l2w (overwrites l1wB)
    wcast_k<<<16384, 256, 0, stream>>>(l2w, l2wB, 8L * BINS * EXPF * BINS);

    // lin2 + residual (in-place on out): out = out + l2wB[c] @ h1T^T
    mgemm_k<true, false, false><<<dim3(4, 8, 16), 256, 0, stream>>>(
        l2wB, (long)BINS * BINS * EXPF, CCH,
        h1T,  (long)WW * BINS * EXPF,
        out,  (long)BINS * WW,
        out,  (long)BINS * WW, BINS, WW, BINS * EXPF);
}

// Round 4
// 636.279 us; speedup vs baseline: 5.1447x; 1.5654x over previous
//
#include <hip/hip_runtime.h>
#include <math.h>

#define BB 2
#define CCH 8
#define BINS 1024
#define WW 512
#define HEADS 16
#define HD 64
#define ROTD 32
#define EXPF 4
#define NXE 8388608L   // B*C*BINS*W

typedef unsigned short ushortT;
typedef short bf16x8 __attribute__((ext_vector_type(8)));
typedef float f32x4 __attribute__((ext_vector_type(4)));

__device__ __forceinline__ ushortT f2bf(float f) {
    unsigned int u = __float_as_uint(f);
    u = (u + 0x7FFF + ((u >> 16) & 1)) >> 16;
    return (ushortT)u;
}
__device__ __forceinline__ float bf2f(ushortT h) {
    return __uint_as_float(((unsigned int)h) << 16);
}
__device__ __forceinline__ float geluf(float x) {
    return 0.5f * x * (1.f + erff(x * 0.70710678118654752f));
}
__device__ __forceinline__ void gl_lds16(const ushortT* g, ushortT* l) {
    __builtin_amdgcn_global_load_lds(
        (const __attribute__((address_space(1))) unsigned int*)g,
        (__attribute__((address_space(3))) unsigned int*)l, 16, 0, 0);
}

// ---------------- weight cast f32 -> bf16 ----------------
__global__ __launch_bounds__(256)
void wcast_k(const float* __restrict__ s, ushortT* __restrict__ d, long n)
{
    long i = ((long)blockIdx.x * 256 + threadIdx.x) * 8;
    if (i >= n) return;
    float4 a = *(const float4*)&s[i];
    float4 b = *(const float4*)&s[i + 4];
    union { ushortT h[8]; uint4 v; } r;
    r.h[0] = f2bf(a.x); r.h[1] = f2bf(a.y); r.h[2] = f2bf(a.z); r.h[3] = f2bf(a.w);
    r.h[4] = f2bf(b.x); r.h[5] = f2bf(b.y); r.h[6] = f2bf(b.z); r.h[7] = f2bf(b.w);
    *(uint4*)&d[i] = r.v;
}

// ---------------- frame norm over BINS, transposed bf16 out [w][f] ----------------
__global__ __launch_bounds__(256)
void normT_k(const float* __restrict__ X, const float* __restrict__ wgt,
             const float* __restrict__ bia, ushortT* __restrict__ YT)
{
    __shared__ float red0[4][64], red1[4][64];
    __shared__ float ms[64], is[64];
    __shared__ float T[64][65];
    const int blk = blockIdx.x;
    const int bc = blk / (WW / 64);
    const int w0 = (blk % (WW / 64)) * 64;
    const int tx = threadIdx.x & 63, ty = threadIdx.x >> 6;
    const float* Xb = X + (long)bc * BINS * WW + w0;
    float s = 0.f, s2 = 0.f;
    for (int f = ty; f < BINS; f += 4) {
        float v = Xb[(long)f * WW + tx];
        s += v; s2 += v * v;
    }
    red0[ty][tx] = s; red1[ty][tx] = s2;
    __syncthreads();
    if (ty == 0) {
        float ss = red0[0][tx] + red0[1][tx] + red0[2][tx] + red0[3][tx];
        float qq = red1[0][tx] + red1[1][tx] + red1[2][tx] + red1[3][tx];
        float m = ss * (1.f / BINS);
        float var = qq * (1.f / BINS) - m * m;
        ms[tx] = m; is[tx] = rsqrtf(var + 1e-5f);
    }
    __syncthreads();
    ushortT* Yb = YT + (long)bc * WW * BINS;
    for (int f0 = 0; f0 < BINS; f0 += 64) {
        #pragma unroll
        for (int fy = 0; fy < 64; fy += 4)
            T[fy + ty][tx] = Xb[(long)(f0 + fy + ty) * WW + tx];
        __syncthreads();
        float wv = wgt[f0 + tx], bv = bia[f0 + tx];
        #pragma unroll
        for (int wy = 0; wy < 64; wy += 4) {
            int w = wy + ty;
            float v = (T[tx][w] - ms[w]) * is[w] * wv + bv;
            Yb[(long)(w0 + w) * BINS + f0 + tx] = f2bf(v);
        }
        __syncthreads();
    }
}

// ---------------- RoPE tables ----------------
__global__ void rope_tab_k(const float* __restrict__ freqs,
                           float* __restrict__ cosT, float* __restrict__ sinT)
{
    int idx = blockIdx.x * 256 + threadIdx.x;   // W*16 = 8192
    if (idx >= WW * 16) return;
    int w = idx >> 4, i = idx & 15;
    float ang = (float)w * freqs[i];
    cosT[idx] = cosf(ang);
    sinT[idx] = sinf(ang);
}

// ---------------- RoPE on bf16 [w][g] layout ----------------
__global__ __launch_bounds__(256)
void ropeB_k(const ushortT* __restrict__ yT, const float* __restrict__ cosT,
             const float* __restrict__ sinT, ushortT* __restrict__ rotT)
{
    long e0 = ((long)blockIdx.x * 256 + threadIdx.x) * 8;
    if (e0 >= NXE) return;
    int g0 = (int)(e0 & 1023);
    int w  = (int)((e0 >> 10) & 511);
    int d0 = g0 & 63;
    union { uint4 v; ushortT h8[8]; } in, ov;
    in.v = *(const uint4*)&yT[e0];
    if (d0 >= ROTD) {
        *(uint4*)&rotT[e0] = in.v;
        return;
    }
    #pragma unroll
    for (int j = 0; j < 8; j += 2) {
        int i = (d0 + j) >> 1;
        float c = cosT[w * 16 + i], s = sinT[w * 16 + i];
        float a = bf2f(in.h8[j]), b = bf2f(in.h8[j + 1]);
        ov.h8[j]     = f2bf(a * c - b * s);
        ov.h8[j + 1] = f2bf(b * c + a * s);
    }
    *(uint4*)&rotT[e0] = ov.v;
}

// ---------------- MFMA flash attention ----------------
// Q=K=rotT [bc][w][g] bf16, V=yT same layout; out oT [bc][w][g] bf16.
// Block: 4 waves, 64 q-rows; wave wv owns rows wv*16..+15.
__global__ __launch_bounds__(256)
void mattn_k(const ushortT* __restrict__ rotT, const ushortT* __restrict__ yT,
             ushortT* __restrict__ oT)
{
    __shared__ ushortT Qs[64 * 64];   // [w][d] xor-swizzled
    __shared__ ushortT Ks[64 * 64];   // [u][d] xor-swizzled
    __shared__ ushortT Vs[64 * 72];   // [d][u] padded
    __shared__ ushortT Ps[64 * 72];   // [w][u] padded, per-wave strips
    const int z = blockIdx.y;
    const int bc = z >> 4, h = z & 15;
    const int wq0 = blockIdx.x * 64;
    const int tid = threadIdx.x;
    const int wv = tid >> 6, l = tid & 63;
    const int lr = l & 15, lk = l >> 4;
    const long hbase = (long)bc * WW * 1024 + h * 64;

    // stage Q once (rows wq0..wq0+63), pre-swizzled global source
    #pragma unroll
    for (int p = 0; p < 2; ++p) {
        int r0 = p * 32 + wv * 8;
        int row = r0 + (l >> 3);
        int gs = (l & 7) ^ (row & 7);
        gl_lds16(rotT + hbase + (long)(wq0 + row) * 1024 + gs * 8, Qs + r0 * 64);
    }

    f32x4 oacc[4] = {};
    float mrow[4] = {-INFINITY, -INFINITY, -INFINITY, -INFINITY};
    float lrow[4] = {0.f, 0.f, 0.f, 0.f};

    for (int u0 = 0; u0 < WW; u0 += 64) {
        #pragma unroll
        for (int p = 0; p < 2; ++p) {
            int r0 = p * 32 + wv * 8;
            int row = r0 + (l >> 3);
            int gs = (l & 7) ^ (row & 7);
            gl_lds16(rotT + hbase + (long)(u0 + row) * 1024 + gs * 8, Ks + r0 * 64);
        }
        // V tile transposed into Vs[d][u]
        #pragma unroll
        for (int rep = 0; rep < 2; ++rep) {
            int ch = rep * 4 + wv;
            union { uint4 v; ushortT h8[8]; } tmp;
            tmp.v = *(const uint4*)(yT + hbase + (long)(u0 + l) * 1024 + ch * 8);
            #pragma unroll
            for (int j = 0; j < 8; ++j)
                Vs[(ch * 8 + j) * 72 + l] = tmp.h8[j];
        }
        __syncthreads();

        // S strip = Q(strip) K^T
        f32x4 sacc[4] = {};
        #pragma unroll
        for (int ko = 0; ko < 2; ++ko) {
            int ar = wv * 16 + lr;
            bf16x8 aq = *(const bf16x8*)&Qs[ar * 64 + (((ko * 4) + lk) ^ (ar & 7)) * 8];
            #pragma unroll
            for (int f = 0; f < 4; ++f) {
                int br = f * 16 + lr;
                bf16x8 bk = *(const bf16x8*)&Ks[br * 64 + (((ko * 4) + lk) ^ (br & 7)) * 8];
                sacc[f] = __builtin_amdgcn_mfma_f32_16x16x32_bf16(aq, bk, sacc[f], 0, 0, 0);
            }
        }

        // online softmax, write P strip to Ps (own-wave rows only)
        #pragma unroll
        for (int rg = 0; rg < 4; ++rg) {
            float s0 = sacc[0][rg] * (1.f / 32.f);
            float s1 = sacc[1][rg] * (1.f / 32.f);
            float s2 = sacc[2][rg] * (1.f / 32.f);
            float s3 = sacc[3][rg] * (1.f / 32.f);
            float mx = fmaxf(fmaxf(s0, s1), fmaxf(s2, s3));
            mx = fmaxf(mx, __shfl_xor(mx, 1));
            mx = fmaxf(mx, __shfl_xor(mx, 2));
            mx = fmaxf(mx, __shfl_xor(mx, 4));
            mx = fmaxf(mx, __shfl_xor(mx, 8));
            float mnew = fmaxf(mrow[rg], mx);
            float al = __expf(mrow[rg] - mnew);
            float p0 = __expf(s0 - mnew), p1 = __expf(s1 - mnew);
            float p2 = __expf(s2 - mnew), p3 = __expf(s3 - mnew);
            float rs = p0 + p1 + p2 + p3;
            rs += __shfl_xor(rs, 1);
            rs += __shfl_xor(rs, 2);
            rs += __shfl_xor(rs, 4);
            rs += __shfl_xor(rs, 8);
            lrow[rg] = lrow[rg] * al + rs;
            mrow[rg] = mnew;
            oacc[0][rg] *= al; oacc[1][rg] *= al;
            oacc[2][rg] *= al; oacc[3][rg] *= al;
            int prow = wv * 16 + lk * 4 + rg;
            Ps[prow * 72 +  0 + lr] = f2bf(p0);
            Ps[prow * 72 + 16 + lr] = f2bf(p1);
            Ps[prow * 72 + 32 + lr] = f2bf(p2);
            Ps[prow * 72 + 48 + lr] = f2bf(p3);
        }
        asm volatile("s_waitcnt lgkmcnt(0)" ::: "memory");

        // O strip += P(strip) V
        #pragma unroll
        for (int ko = 0; ko < 2; ++ko) {
            int ar = wv * 16 + lr;
            bf16x8 ap = *(const bf16x8*)&Ps[ar * 72 + ko * 32 + lk * 8];
            #pragma unroll
            for (int f = 0; f < 4; ++f) {
                bf16x8 bv = *(const bf16x8*)&Vs[(f * 16 + lr) * 72 + ko * 32 + lk * 8];
                oacc[f] = __builtin_amdgcn_mfma_f32_16x16x32_bf16(ap, bv, oacc[f], 0, 0, 0);
            }
        }
        __syncthreads();
    }

    // epilogue: O/l -> oT[bc][w][h*64+d]
    #pragma unroll
    for (int rg = 0; rg < 4; ++rg) {
        float inv = 1.f / lrow[rg];
        int w = wq0 + wv * 16 + lk * 4 + rg;
        long b2 = (long)bc * WW * 1024 + (long)w * 1024 + h * 64;
        #pragma unroll
        for (int f = 0; f < 4; ++f)
            oT[b2 + f * 16 + lr] = f2bf(oacc[f][rg] * inv);
    }
}

// ---------------- bf16 MFMA GEMM ----------------
// C[z][M][N] = A[z%aMod][M][K] @ B[z][N][K]^T  (both operands k-contiguous bf16)
// TRANSOUT: write bf16 C^T [N][M] (optional GELU). Else fp32 [M][N] (+R).
template<bool HASRES, bool GELUF, bool TRANSOUT>
__global__ __launch_bounds__(256)
void mgemm_k(const ushortT* __restrict__ A, long sA, int aMod,
             const ushortT* __restrict__ B, long sB,
             void* __restrict__ Cp, long sC,
             const float* __restrict__ R, long sR,
             int M, int N, int K)
{
    __shared__ ushortT smem[(128 + 128) * 64];
    ushortT* As = smem;
    ushortT* Bs = smem + 128 * 64;
    const int z = blockIdx.z;
    const ushortT* Ab = A + (long)(z % aMod) * sA + (long)blockIdx.y * 128 * K;
    const ushortT* Bb = B + (long)z * sB + (long)blockIdx.x * 128 * K;
    const int tid = threadIdx.x;
    const int wv = tid >> 6, l = tid & 63;
    const int lrow = l & 15, lk = l >> 4;
    const int mb = (wv >> 1) * 64, nb = (wv & 1) * 64;
    f32x4 acc[4][4] = {};

    for (int k0 = 0; k0 < K; k0 += 64) {
        #pragma unroll
        for (int t = 0; t < 4; ++t) {
            int r0 = wv * 32 + t * 8;
            int row = r0 + (l >> 3);
            int gs = (l & 7) ^ (row & 7);
            gl_lds16(Ab + (long)row * K + k0 + gs * 8, As + r0 * 64);
            gl_lds16(Bb + (long)row * K + k0 + gs * 8, Bs + r0 * 64);
        }
        __syncthreads();
        #pragma unroll
        for (int ko = 0; ko < 2; ++ko) {
            bf16x8 af[4], bg[4];
            #pragma unroll
            for (int i = 0; i < 4; ++i) {
                int ra = mb + i * 16 + lrow;
                af[i] = *(const bf16x8*)&As[ra * 64 + ((lk + ko * 4) ^ (ra & 7)) * 8];
                int rb = nb + i * 16 + lrow;
                bg[i] = *(const bf16x8*)&Bs[rb * 64 + ((lk + ko * 4) ^ (rb & 7)) * 8];
            }
            #pragma unroll
            for (int i = 0; i < 4; ++i)
                #pragma unroll
                for (int j = 0; j < 4; ++j)
                    acc[i][j] = __builtin_amdgcn_mfma_f32_16x16x32_bf16(
                        af[i], bg[j], acc[i][j], 0, 0, 0);
        }
        __syncthreads();
    }

    const int m0g = blockIdx.y * 128 + mb, n0g = blockIdx.x * 128 + nb;
    if (!TRANSOUT) {
        float* Cf = (float*)Cp + (long)z * sC;
        #pragma unroll
        for (int i = 0; i < 4; ++i)
            #pragma unroll
            for (int j = 0; j < 4; ++j)
                #pragma unroll
                for (int rg = 0; rg < 4; ++rg) {
                    long m = m0g + i * 16 + lk * 4 + rg;
                    long n = n0g + j * 16 + lrow;
                    float v = acc[i][j][rg];
                    if (GELUF) v = geluf(v);
                    if (HASRES) v += R[(long)z * sR + m * N + n];
                    Cf[m * N + n] = v;
                }
    } else {
        ushortT* Ts = smem + wv * 4096;
        #pragma unroll
        for (int i = 0; i < 4; ++i)
            #pragma unroll
            for (int j = 0; j < 4; ++j)
                #pragma unroll
                for (int rg = 0; rg < 4; ++rg) {
                    int ml = i * 16 + lk * 4 + rg;
                    int nl = j * 16 + lrow;
                    float v = acc[i][j][rg];
                    if (GELUF) v = geluf(v);
                    Ts[nl * 64 + (((ml >> 3) ^ (nl & 7)) << 3) + (ml & 7)] = f2bf(v);
                }
        __syncthreads();
        ushortT* CT = (ushortT*)Cp + (long)z * sC;
        #pragma unroll
        for (int p = 0; p < 8; ++p) {
            int nl = p * 8 + (l >> 3), mc = l & 7;
            uint4 d = *(const uint4*)&Ts[nl * 64 + ((mc ^ (nl & 7)) << 3)];
            *(uint4*)&CT[(long)(n0g + nl) * M + m0g + mc * 8] = d;
        }
    }
}

extern "C" void kernel_launch(void* const* d_in, const int* in_sizes, int n_in,
                              void* d_out, int out_size, void* d_ws, size_t ws_size,
                              hipStream_t stream)
{
    const float* x    = (const float*)d_in[0];
    const float* n1w  = (const float*)d_in[1];
    const float* n1b  = (const float*)d_in[2];
    const float* freqs= (const float*)d_in[3];
    const float* qw   = (const float*)d_in[4];
    const float* ow   = (const float*)d_in[5];
    const float* n2w  = (const float*)d_in[6];
    const float* n2b  = (const float*)d_in[7];
    const float* l1w  = (const float*)d_in[8];
    const float* l2w  = (const float*)d_in[9];
    float* out = (float*)d_out;
    char* wsb  = (char*)d_ws;
    const long MB = 1L << 20;

    // workspace (max live 160MB + tables):
    ushortT* qwB  = (ushortT*)(wsb +   0 * MB);   // dead after qproj
    ushortT* owB  = (ushortT*)(wsb +  16 * MB);   // dead after outproj
    ushortT* znT  = (ushortT*)(wsb +  32 * MB);   // dead after qproj
    ushortT* CfT  = (ushortT*)(wsb +  32 * MB);   // attn out (znT slot)
    ushortT* l1wB = (ushortT*)(wsb +   0 * MB);   // cast after outproj
    ushortT* l2wB = (ushortT*)(wsb +   0 * MB);   // cast after lin1
    ushortT* yT   = (ushortT*)(wsb +  64 * MB);   // qproj out, dead after attn
    ushortT* zn2T = (ushortT*)(wsb +  64 * MB);   // after yT dead
    ushortT* rotT = (ushortT*)(wsb +  80 * MB);   // dead after attn
    ushortT* h1T  = (ushortT*)(wsb +  96 * MB);   // 64MB
    float*   cosT = (float*)  (wsb + 160 * MB);
    float*   sinT = cosT + WW * 16;

    rope_tab_k<<<32, 256, 0, stream>>>(freqs, cosT, sinT);

    wcast_k<<<4096, 256, 0, stream>>>(qw, qwB, 8L * BINS * BINS);
    wcast_k<<<4096, 256, 0, stream>>>(ow, owB, 8L * BINS * BINS);

    // norm1: x -> znT (bf16 [w][f])
    normT_k<<<BB * CCH * (WW / 64), 256, 0, stream>>>(x, n1w, n1b, znT);

    // qproj, transposed bf16 out: yT[bc][w][g]
    mgemm_k<false, false, true><<<dim3(4, 8, 16), 256, 0, stream>>>(
        qwB, (long)BINS * BINS, CCH,
        znT, (long)WW * BINS,
        yT,  (long)WW * BINS,
        nullptr, 0, BINS, WW, BINS);

    // rope: yT -> rotT (bf16)
    ropeB_k<<<4096, 256, 0, stream>>>(yT, cosT, sinT, rotT);

    // MFMA flash attention -> CfT [bc][w][g]
    mattn_k<<<dim3(8, 256), 256, 0, stream>>>(rotT, yT, CfT);

    // outproj + residual: out = x + owB[c] @ CfT^T
    mgemm_k<true, false, false><<<dim3(4, 8, 16), 256, 0, stream>>>(
        owB, (long)BINS * BINS, CCH,
        CfT, (long)WW * BINS,
        out, (long)BINS * WW,
        x,   (long)BINS * WW, BINS, WW, BINS);

    // cast l1w (overwrites qwB/owB/CfT region)
    wcast_k<<<16384, 256, 0, stream>>>(l1w, l1wB, 8L * BINS * EXPF * BINS);

    // norm2: out -> zn2T (bf16 [w][f])
    normT_k<<<BB * CCH * (WW / 64), 256, 0, stream>>>(out, n2w, n2b, zn2T);

    // lin1 + GELU, transposed bf16 out: h1T [w][4096]
    mgemm_k<false, true, true><<<dim3(4, 32, 16), 256, 0, stream>>>(
        l1wB, (long)BINS * EXPF * BINS, CCH,
        zn2T, (long)WW * BINS,
        h1T,  (long)WW * BINS * EXPF,
        nullptr, 0, BINS * EXPF, WW, BINS);

    // cast l2w (overwrites l1wB)
    wcast_k<<<16384, 256, 0, stream>>>(l2w, l2wB, 8L * BINS * EXPF * BINS);

    // lin2 + residual (in-place on out)
    mgemm_k<true, false, false><<<dim3(4, 8, 16), 256, 0, stream>>>(
        l2wB, (long)BINS * BINS * EXPF, CCH,
        h1T,  (long)WW * BINS * EXPF,
        out,  (long)BINS * WW,
        out,  (long)BINS * WW, BINS, WW, BINS * EXPF);
}

// Round 5
// 477.068 us; speedup vs baseline: 6.8617x; 1.3337x over previous
//
#include <hip/hip_runtime.h>
#include <math.h>

#define BB 2
#define CCH 8
#define BINS 1024
#define WW 512
#define HEADS 16
#define HD 64
#define ROTD 32
#define EXPF 4
#define NXE 8388608L   // B*C*BINS*W
#define NTW 32         // w-columns per norm block

typedef unsigned short ushortT;
typedef short bf16x8 __attribute__((ext_vector_type(8)));
typedef float f32x4 __attribute__((ext_vector_type(4)));

__device__ __forceinline__ ushortT f2bf(float f) {
    unsigned int u = __float_as_uint(f);
    u = (u + 0x7FFF + ((u >> 16) & 1)) >> 16;
    return (ushortT)u;
}
__device__ __forceinline__ float bf2f(ushortT h) {
    return __uint_as_float(((unsigned int)h) << 16);
}
__device__ __forceinline__ float geluf(float x) {
    return 0.5f * x * (1.f + erff(x * 0.70710678118654752f));
}
__device__ __forceinline__ void gl_lds16(const ushortT* g, ushortT* l) {
    __builtin_amdgcn_global_load_lds(
        (const __attribute__((address_space(1))) unsigned int*)g,
        (__attribute__((address_space(3))) unsigned int*)l, 16, 0, 0);
}

// ---------------- weight cast f32 -> bf16 ----------------
__global__ __launch_bounds__(256)
void wcast_k(const float* __restrict__ s, ushortT* __restrict__ d, long n)
{
    long i = ((long)blockIdx.x * 256 + threadIdx.x) * 8;
    if (i >= n) return;
    float4 a = *(const float4*)&s[i];
    float4 b = *(const float4*)&s[i + 4];
    union { ushortT h[8]; uint4 v; } r;
    r.h[0] = f2bf(a.x); r.h[1] = f2bf(a.y); r.h[2] = f2bf(a.z); r.h[3] = f2bf(a.w);
    r.h[4] = f2bf(b.x); r.h[5] = f2bf(b.y); r.h[6] = f2bf(b.z); r.h[7] = f2bf(b.w);
    *(uint4*)&d[i] = r.v;
}

// ---------------- frame norm over BINS, transposed bf16 out [w][f] ----------------
// One block per (bc, 32-w tile): stage [1024][32] fp32 tile in LDS (single HBM
// read), register-accumulate stats, emit transposed bf16 with uint4 stores.
__global__ __launch_bounds__(1024)
void normT_k(const float* __restrict__ X, const float* __restrict__ wgt,
             const float* __restrict__ bia, ushortT* __restrict__ YT)
{
    __shared__ float tile[NTW][BINS + 1];   // +1: staging write conflict-free
    __shared__ float red0[32][NTW], red1[32][NTW];
    __shared__ float ms[NTW], is[NTW];
    const int bc = blockIdx.x >> 4;              // W/NTW = 16 tiles
    const int w0 = (blockIdx.x & 15) * NTW;
    const int tid = threadIdx.x;
    const int w  = tid & (NTW - 1);
    const int fy = tid >> 5;                      // 0..31
    const float* Xb = X + (long)bc * BINS * WW + w0;
    float s = 0.f, s2 = 0.f;
    for (int f = fy; f < BINS; f += 32) {
        float v = Xb[(long)f * WW + w];
        s += v; s2 += v * v;
        tile[w][f] = v;
    }
    red0[fy][w] = s; red1[fy][w] = s2;
    __syncthreads();
    if (tid < NTW) {
        float ss = 0.f, qq = 0.f;
        #pragma unroll
        for (int j = 0; j < 32; ++j) { ss += red0[j][tid]; qq += red1[j][tid]; }
        float m = ss * (1.f / BINS);
        float var = qq * (1.f / BINS) - m * m;
        ms[tid] = m; is[tid] = rsqrtf(var + 1e-5f);
    }
    __syncthreads();
    const int w2 = tid >> 5;       // output row (w) this thread handles
    const int c  = tid & 31;       // f-chunk index
    float m = ms[w2], inv = is[w2];
    ushortT* Yb = YT + ((long)bc * WW + w0 + w2) * BINS;
    #pragma unroll
    for (int jj = 0; jj < 4; ++jj) {
        int f0 = jj * 256 + c * 8;
        union { ushortT h[8]; uint4 v; } r;
        #pragma unroll
        for (int e = 0; e < 8; ++e) {
            int f = f0 + e;
            float v = (tile[w2][f] - m) * inv * wgt[f] + bia[f];
            r.h[e] = f2bf(v);
        }
        *(uint4*)&Yb[f0] = r.v;
    }
}

// ---------------- RoPE tables ----------------
__global__ void rope_tab_k(const float* __restrict__ freqs,
                           float* __restrict__ cosT, float* __restrict__ sinT)
{
    int idx = blockIdx.x * 256 + threadIdx.x;   // W*16 = 8192
    if (idx >= WW * 16) return;
    int w = idx >> 4, i = idx & 15;
    float ang = (float)w * freqs[i];
    cosT[idx] = cosf(ang);
    sinT[idx] = sinf(ang);
}

// ---------------- RoPE on bf16 [w][g] layout ----------------
__global__ __launch_bounds__(256)
void ropeB_k(const ushortT* __restrict__ yT, const float* __restrict__ cosT,
             const float* __restrict__ sinT, ushortT* __restrict__ rotT)
{
    long e0 = ((long)blockIdx.x * 256 + threadIdx.x) * 8;
    if (e0 >= NXE) return;
    int g0 = (int)(e0 & 1023);
    int w  = (int)((e0 >> 10) & 511);
    int d0 = g0 & 63;
    union { uint4 v; ushortT h8[8]; } in, ov;
    in.v = *(const uint4*)&yT[e0];
    if (d0 >= ROTD) {
        *(uint4*)&rotT[e0] = in.v;
        return;
    }
    #pragma unroll
    for (int j = 0; j < 8; j += 2) {
        int i = (d0 + j) >> 1;
        float c = cosT[w * 16 + i], s = sinT[w * 16 + i];
        float a = bf2f(in.h8[j]), b = bf2f(in.h8[j + 1]);
        ov.h8[j]     = f2bf(a * c - b * s);
        ov.h8[j + 1] = f2bf(b * c + a * s);
    }
    *(uint4*)&rotT[e0] = ov.v;
}

// ---------------- MFMA flash attention ----------------
// Q=K=rotT [bc][w][g] bf16, V=yT same layout; out oT [bc][w][g] bf16.
__global__ __launch_bounds__(256)
void mattn_k(const ushortT* __restrict__ rotT, const ushortT* __restrict__ yT,
             ushortT* __restrict__ oT)
{
    __shared__ ushortT Qs[64 * 64];   // [w][d] xor-swizzled
    __shared__ ushortT Ks[64 * 64];   // [u][d] xor-swizzled
    __shared__ ushortT Vs[64 * 72];   // [d][u] padded
    __shared__ ushortT Ps[64 * 72];   // [w][u] padded, per-wave strips
    const int z = blockIdx.y;
    const int bc = z >> 4, h = z & 15;
    const int wq0 = blockIdx.x * 64;
    const int tid = threadIdx.x;
    const int wv = tid >> 6, l = tid & 63;
    const int lr = l & 15, lk = l >> 4;
    const long hbase = (long)bc * WW * 1024 + h * 64;

    #pragma unroll
    for (int p = 0; p < 2; ++p) {
        int r0 = p * 32 + wv * 8;
        int row = r0 + (l >> 3);
        int gs = (l & 7) ^ (row & 7);
        gl_lds16(rotT + hbase + (long)(wq0 + row) * 1024 + gs * 8, Qs + r0 * 64);
    }

    f32x4 oacc[4] = {};
    float mrow[4] = {-INFINITY, -INFINITY, -INFINITY, -INFINITY};
    float lrow[4] = {0.f, 0.f, 0.f, 0.f};

    for (int u0 = 0; u0 < WW; u0 += 64) {
        #pragma unroll
        for (int p = 0; p < 2; ++p) {
            int r0 = p * 32 + wv * 8;
            int row = r0 + (l >> 3);
            int gs = (l & 7) ^ (row & 7);
            gl_lds16(rotT + hbase + (long)(u0 + row) * 1024 + gs * 8, Ks + r0 * 64);
        }
        #pragma unroll
        for (int rep = 0; rep < 2; ++rep) {
            int ch = rep * 4 + wv;
            union { uint4 v; ushortT h8[8]; } tmp;
            tmp.v = *(const uint4*)(yT + hbase + (long)(u0 + l) * 1024 + ch * 8);
            #pragma unroll
            for (int j = 0; j < 8; ++j)
                Vs[(ch * 8 + j) * 72 + l] = tmp.h8[j];
        }
        __syncthreads();

        f32x4 sacc[4] = {};
        #pragma unroll
        for (int ko = 0; ko < 2; ++ko) {
            int ar = wv * 16 + lr;
            bf16x8 aq = *(const bf16x8*)&Qs[ar * 64 + (((ko * 4) + lk) ^ (ar & 7)) * 8];
            #pragma unroll
            for (int f = 0; f < 4; ++f) {
                int br = f * 16 + lr;
                bf16x8 bk = *(const bf16x8*)&Ks[br * 64 + (((ko * 4) + lk) ^ (br & 7)) * 8];
                sacc[f] = __builtin_amdgcn_mfma_f32_16x16x32_bf16(aq, bk, sacc[f], 0, 0, 0);
            }
        }

        #pragma unroll
        for (int rg = 0; rg < 4; ++rg) {
            float s0 = sacc[0][rg] * (1.f / 32.f);
            float s1 = sacc[1][rg] * (1.f / 32.f);
            float s2 = sacc[2][rg] * (1.f / 32.f);
            float s3 = sacc[3][rg] * (1.f / 32.f);
            float mx = fmaxf(fmaxf(s0, s1), fmaxf(s2, s3));
            mx = fmaxf(mx, __shfl_xor(mx, 1));
            mx = fmaxf(mx, __shfl_xor(mx, 2));
            mx = fmaxf(mx, __shfl_xor(mx, 4));
            mx = fmaxf(mx, __shfl_xor(mx, 8));
            float mnew = fmaxf(mrow[rg], mx);
            float al = __expf(mrow[rg] - mnew);
            float p0 = __expf(s0 - mnew), p1 = __expf(s1 - mnew);
            float p2 = __expf(s2 - mnew), p3 = __expf(s3 - mnew);
            float rs = p0 + p1 + p2 + p3;
            rs += __shfl_xor(rs, 1);
            rs += __shfl_xor(rs, 2);
            rs += __shfl_xor(rs, 4);
            rs += __shfl_xor(rs, 8);
            lrow[rg] = lrow[rg] * al + rs;
            mrow[rg] = mnew;
            oacc[0][rg] *= al; oacc[1][rg] *= al;
            oacc[2][rg] *= al; oacc[3][rg] *= al;
            int prow = wv * 16 + lk * 4 + rg;
            Ps[prow * 72 +  0 + lr] = f2bf(p0);
            Ps[prow * 72 + 16 + lr] = f2bf(p1);
            Ps[prow * 72 + 32 + lr] = f2bf(p2);
            Ps[prow * 72 + 48 + lr] = f2bf(p3);
        }
        asm volatile("s_waitcnt lgkmcnt(0)" ::: "memory");

        #pragma unroll
        for (int ko = 0; ko < 2; ++ko) {
            int ar = wv * 16 + lr;
            bf16x8 ap = *(const bf16x8*)&Ps[ar * 72 + ko * 32 + lk * 8];
            #pragma unroll
            for (int f = 0; f < 4; ++f) {
                bf16x8 bv = *(const bf16x8*)&Vs[(f * 16 + lr) * 72 + ko * 32 + lk * 8];
                oacc[f] = __builtin_amdgcn_mfma_f32_16x16x32_bf16(ap, bv, oacc[f], 0, 0, 0);
            }
        }
        __syncthreads();
    }

    #pragma unroll
    for (int rg = 0; rg < 4; ++rg) {
        float inv = 1.f / lrow[rg];
        int w = wq0 + wv * 16 + lk * 4 + rg;
        long b2 = (long)bc * WW * 1024 + (long)w * 1024 + h * 64;
        #pragma unroll
        for (int f = 0; f < 4; ++f)
            oT[b2 + f * 16 + lr] = f2bf(oacc[f][rg] * inv);
    }
}

// ---------------- bf16 MFMA GEMM ----------------
// C[z][M][N] = A[z%aMod][M][K] @ B[z][N][K]^T  (both operands k-contiguous bf16)
// TRANSOUT: write bf16 C^T [N][M] (optional GELU). Else fp32 [M][N] (+R).
template<bool HASRES, bool GELUF, bool TRANSOUT>
__global__ __launch_bounds__(256)
void mgemm_k(const ushortT* __restrict__ A, long sA, int aMod,
             const ushortT* __restrict__ B, long sB,
             void* __restrict__ Cp, long sC,
             const float* __restrict__ R, long sR,
             int M, int N, int K)
{
    __shared__ ushortT smem[(128 + 128) * 64];
    ushortT* As = smem;
    ushortT* Bs = smem + 128 * 64;
    const int z = blockIdx.z;
    const ushortT* Ab = A + (long)(z % aMod) * sA + (long)blockIdx.y * 128 * K;
    const ushortT* Bb = B + (long)z * sB + (long)blockIdx.x * 128 * K;
    const int tid = threadIdx.x;
    const int wv = tid >> 6, l = tid & 63;
    const int lrow = l & 15, lk = l >> 4;
    const int mb = (wv >> 1) * 64, nb = (wv & 1) * 64;
    f32x4 acc[4][4] = {};

    for (int k0 = 0; k0 < K; k0 += 64) {
        #pragma unroll
        for (int t = 0; t < 4; ++t) {
            int r0 = wv * 32 + t * 8;
            int row = r0 + (l >> 3);
            int gs = (l & 7) ^ (row & 7);
            gl_lds16(Ab + (long)row * K + k0 + gs * 8, As + r0 * 64);
            gl_lds16(Bb + (long)row * K + k0 + gs * 8, Bs + r0 * 64);
        }
        __syncthreads();
        #pragma unroll
        for (int ko = 0; ko < 2; ++ko) {
            bf16x8 af[4], bg[4];
            #pragma unroll
            for (int i = 0; i < 4; ++i) {
                int ra = mb + i * 16 + lrow;
                af[i] = *(const bf16x8*)&As[ra * 64 + ((lk + ko * 4) ^ (ra & 7)) * 8];
                int rb = nb + i * 16 + lrow;
                bg[i] = *(const bf16x8*)&Bs[rb * 64 + ((lk + ko * 4) ^ (rb & 7)) * 8];
            }
            #pragma unroll
            for (int i = 0; i < 4; ++i)
                #pragma unroll
                for (int j = 0; j < 4; ++j)
                    acc[i][j] = __builtin_amdgcn_mfma_f32_16x16x32_bf16(
                        af[i], bg[j], acc[i][j], 0, 0, 0);
        }
        __syncthreads();
    }

    const int m0g = blockIdx.y * 128 + mb, n0g = blockIdx.x * 128 + nb;
    if (!TRANSOUT) {
        float* Cf = (float*)Cp + (long)z * sC;
        #pragma unroll
        for (int i = 0; i < 4; ++i)
            #pragma unroll
            for (int j = 0; j < 4; ++j)
                #pragma unroll
                for (int rg = 0; rg < 4; ++rg) {
                    long m = m0g + i * 16 + lk * 4 + rg;
                    long n = n0g + j * 16 + lrow;
                    float v = acc[i][j][rg];
                    if (GELUF) v = geluf(v);
                    if (HASRES) v += R[(long)z * sR + m * N + n];
                    Cf[m * N + n] = v;
                }
    } else {
        ushortT* Ts = smem + wv * 4096;
        #pragma unroll
        for (int i = 0; i < 4; ++i)
            #pragma unroll
            for (int j = 0; j < 4; ++j)
                #pragma unroll
                for (int rg = 0; rg < 4; ++rg) {
                    int ml = i * 16 + lk * 4 + rg;
                    int nl = j * 16 + lrow;
                    float v = acc[i][j][rg];
                    if (GELUF) v = geluf(v);
                    Ts[nl * 64 + (((ml >> 3) ^ (nl & 7)) << 3) + (ml & 7)] = f2bf(v);
                }
        __syncthreads();
        ushortT* CT = (ushortT*)Cp + (long)z * sC;
        #pragma unroll
        for (int p = 0; p < 8; ++p) {
            int nl = p * 8 + (l >> 3), mc = l & 7;
            uint4 d = *(const uint4*)&Ts[nl * 64 + ((mc ^ (nl & 7)) << 3)];
            *(uint4*)&CT[(long)(n0g + nl) * M + m0g + mc * 8] = d;
        }
    }
}

extern "C" void kernel_launch(void* const* d_in, const int* in_sizes, int n_in,
                              void* d_out, int out_size, void* d_ws, size_t ws_size,
                              hipStream_t stream)
{
    const float* x    = (const float*)d_in[0];
    const float* n1w  = (const float*)d_in[1];
    const float* n1b  = (const float*)d_in[2];
    const float* freqs= (const float*)d_in[3];
    const float* qw   = (const float*)d_in[4];
    const float* ow   = (const float*)d_in[5];
    const float* n2w  = (const float*)d_in[6];
    const float* n2b  = (const float*)d_in[7];
    const float* l1w  = (const float*)d_in[8];
    const float* l2w  = (const float*)d_in[9];
    float* out = (float*)d_out;
    char* wsb  = (char*)d_ws;
    const long MB = 1L << 20;

    ushortT* qwB  = (ushortT*)(wsb +   0 * MB);
    ushortT* owB  = (ushortT*)(wsb +  16 * MB);
    ushortT* znT  = (ushortT*)(wsb +  32 * MB);
    ushortT* CfT  = (ushortT*)(wsb +  32 * MB);
    ushortT* l1wB = (ushortT*)(wsb +   0 * MB);
    ushortT* l2wB = (ushortT*)(wsb +   0 * MB);
    ushortT* yT   = (ushortT*)(wsb +  64 * MB);
    ushortT* zn2T = (ushortT*)(wsb +  64 * MB);
    ushortT* rotT = (ushortT*)(wsb +  80 * MB);
    ushortT* h1T  = (ushortT*)(wsb +  96 * MB);
    float*   cosT = (float*)  (wsb + 160 * MB);
    float*   sinT = cosT + WW * 16;

    rope_tab_k<<<32, 256, 0, stream>>>(freqs, cosT, sinT);

    wcast_k<<<4096, 256, 0, stream>>>(qw, qwB, 8L * BINS * BINS);
    wcast_k<<<4096, 256, 0, stream>>>(ow, owB, 8L * BINS * BINS);

    // norm1: x -> znT (bf16 [w][f])
    normT_k<<<BB * CCH * 16, 1024, 0, stream>>>(x, n1w, n1b, znT);

    // qproj, transposed bf16 out: yT[bc][w][g]
    mgemm_k<false, false, true><<<dim3(4, 8, 16), 256, 0, stream>>>(
        qwB, (long)BINS * BINS, CCH,
        znT, (long)WW * BINS,
        yT,  (long)WW * BINS,
        nullptr, 0, BINS, WW, BINS);

    // rope: yT -> rotT (bf16)
    ropeB_k<<<4096, 256, 0, stream>>>(yT, cosT, sinT, rotT);

    // MFMA flash attention -> CfT [bc][w][g]
    mattn_k<<<dim3(8, 256), 256, 0, stream>>>(rotT, yT, CfT);

    // outproj + residual: out = x + owB[c] @ CfT^T
    mgemm_k<true, false, false><<<dim3(4, 8, 16), 256, 0, stream>>>(
        owB, (long)BINS * BINS, CCH,
        CfT, (long)WW * BINS,
        out, (long)BINS * WW,
        x,   (long)BINS * WW, BINS, WW, BINS);

    // cast l1w (overwrites qwB/owB/CfT region)
    wcast_k<<<16384, 256, 0, stream>>>(l1w, l1wB, 8L * BINS * EXPF * BINS);

    // norm2: out -> zn2T (bf16 [w][f])
    normT_k<<<BB * CCH * 16, 1024, 0, stream>>>(out, n2w, n2b, zn2T);

    // lin1 + GELU, transposed bf16 out: h1T [w][4096]
    mgemm_k<false, true, true><<<dim3(4, 32, 16), 256, 0, stream>>>(
        l1wB, (long)BINS * EXPF * BINS, CCH,
        zn2T, (long)WW * BINS,
        h1T,  (long)WW * BINS * EXPF,
        nullptr, 0, BINS * EXPF, WW, BINS);

    // cast l2w (overwrites l1wB)
    wcast_k<<<16384, 256, 0, stream>>>(l2w, l2wB, 8L * BINS * EXPF * BINS);

    // lin2 + residual (in-place on out)
    mgemm_k<true, false, false><<<dim3(4, 8, 16), 256, 0, stream>>>(
        l2wB, (long)BINS * BINS * EXPF, CCH,
        h1T,  (long)WW * BINS * EXPF,
        out,  (long)BINS * WW,
        out,  (long)BINS * WW, BINS, WW, BINS * EXPF);
}

// Round 6
// 457.683 us; speedup vs baseline: 7.1523x; 1.0424x over previous
//
#include <hip/hip_runtime.h>
#include <math.h>

#define BB 2
#define CCH 8
#define BINS 1024
#define WW 512
#define HEADS 16
#define HD 64
#define ROTD 32
#define EXPF 4
#define NXE 8388608L   // B*C*BINS*W
#define NTW 32         // w-columns per norm block

typedef unsigned short ushortT;
typedef short bf16x8 __attribute__((ext_vector_type(8)));
typedef float f32x4 __attribute__((ext_vector_type(4)));

__device__ __forceinline__ ushortT f2bf(float f) {
    unsigned int u = __float_as_uint(f);
    u = (u + 0x7FFF + ((u >> 16) & 1)) >> 16;
    return (ushortT)u;
}
__device__ __forceinline__ float bf2f(ushortT h) {
    return __uint_as_float(((unsigned int)h) << 16);
}
__device__ __forceinline__ float geluf(float x) {
    return 0.5f * x * (1.f + erff(x * 0.70710678118654752f));
}
__device__ __forceinline__ void gl_lds16(const ushortT* g, ushortT* l) {
    __builtin_amdgcn_global_load_lds(
        (const __attribute__((address_space(1))) unsigned int*)g,
        (__attribute__((address_space(3))) unsigned int*)l, 16, 0, 0);
}

// ---------------- frame norm over BINS, transposed bf16 out [w][f] ----------------
__global__ __launch_bounds__(1024)
void normT_k(const float* __restrict__ X, const float* __restrict__ wgt,
             const float* __restrict__ bia, ushortT* __restrict__ YT)
{
    __shared__ float tile[NTW][BINS + 1];
    __shared__ float red0[32][NTW], red1[32][NTW];
    __shared__ float ms[NTW], is[NTW];
    const int bc = blockIdx.x >> 4;
    const int w0 = (blockIdx.x & 15) * NTW;
    const int tid = threadIdx.x;
    const int w  = tid & (NTW - 1);
    const int fy = tid >> 5;
    const float* Xb = X + (long)bc * BINS * WW + w0;
    float s = 0.f, s2 = 0.f;
    for (int f = fy; f < BINS; f += 32) {
        float v = Xb[(long)f * WW + w];
        s += v; s2 += v * v;
        tile[w][f] = v;
    }
    red0[fy][w] = s; red1[fy][w] = s2;
    __syncthreads();
    if (tid < NTW) {
        float ss = 0.f, qq = 0.f;
        #pragma unroll
        for (int j = 0; j < 32; ++j) { ss += red0[j][tid]; qq += red1[j][tid]; }
        float m = ss * (1.f / BINS);
        float var = qq * (1.f / BINS) - m * m;
        ms[tid] = m; is[tid] = rsqrtf(var + 1e-5f);
    }
    __syncthreads();
    const int w2 = tid >> 5;
    const int c  = tid & 31;
    float m = ms[w2], inv = is[w2];
    ushortT* Yb = YT + ((long)bc * WW + w0 + w2) * BINS;
    #pragma unroll
    for (int jj = 0; jj < 4; ++jj) {
        int f0 = jj * 256 + c * 8;
        union { ushortT h[8]; uint4 v; } r;
        #pragma unroll
        for (int e = 0; e < 8; ++e) {
            int f = f0 + e;
            float v = (tile[w2][f] - m) * inv * wgt[f] + bia[f];
            r.h[e] = f2bf(v);
        }
        *(uint4*)&Yb[f0] = r.v;
    }
}

// ---------------- RoPE tables ----------------
__global__ void rope_tab_k(const float* __restrict__ freqs,
                           float* __restrict__ cosT, float* __restrict__ sinT)
{
    int idx = blockIdx.x * 256 + threadIdx.x;
    if (idx >= WW * 16) return;
    int w = idx >> 4, i = idx & 15;
    float ang = (float)w * freqs[i];
    cosT[idx] = cosf(ang);
    sinT[idx] = sinf(ang);
}

// ---------------- RoPE on bf16 [w][g] layout ----------------
__global__ __launch_bounds__(256)
void ropeB_k(const ushortT* __restrict__ yT, const float* __restrict__ cosT,
             const float* __restrict__ sinT, ushortT* __restrict__ rotT)
{
    long e0 = ((long)blockIdx.x * 256 + threadIdx.x) * 8;
    if (e0 >= NXE) return;
    int g0 = (int)(e0 & 1023);
    int w  = (int)((e0 >> 10) & 511);
    int d0 = g0 & 63;
    union { uint4 v; ushortT h8[8]; } in, ov;
    in.v = *(const uint4*)&yT[e0];
    if (d0 >= ROTD) {
        *(uint4*)&rotT[e0] = in.v;
        return;
    }
    #pragma unroll
    for (int j = 0; j < 8; j += 2) {
        int i = (d0 + j) >> 1;
        float c = cosT[w * 16 + i], s = sinT[w * 16 + i];
        float a = bf2f(in.h8[j]), b = bf2f(in.h8[j + 1]);
        ov.h8[j]     = f2bf(a * c - b * s);
        ov.h8[j + 1] = f2bf(b * c + a * s);
    }
    *(uint4*)&rotT[e0] = ov.v;
}

// ---------------- MFMA flash attention ----------------
__global__ __launch_bounds__(256)
void mattn_k(const ushortT* __restrict__ rotT, const ushortT* __restrict__ yT,
             ushortT* __restrict__ oT)
{
    __shared__ ushortT Qs[64 * 64];
    __shared__ ushortT Ks[64 * 64];
    __shared__ ushortT Vs[64 * 72];
    __shared__ ushortT Ps[64 * 72];
    const int z = blockIdx.y;
    const int bc = z >> 4, h = z & 15;
    const int wq0 = blockIdx.x * 64;
    const int tid = threadIdx.x;
    const int wv = tid >> 6, l = tid & 63;
    const int lr = l & 15, lk = l >> 4;
    const long hbase = (long)bc * WW * 1024 + h * 64;

    #pragma unroll
    for (int p = 0; p < 2; ++p) {
        int r0 = p * 32 + wv * 8;
        int row = r0 + (l >> 3);
        int gs = (l & 7) ^ (row & 7);
        gl_lds16(rotT + hbase + (long)(wq0 + row) * 1024 + gs * 8, Qs + r0 * 64);
    }

    f32x4 oacc[4] = {};
    float mrow[4] = {-INFINITY, -INFINITY, -INFINITY, -INFINITY};
    float lrow[4] = {0.f, 0.f, 0.f, 0.f};

    for (int u0 = 0; u0 < WW; u0 += 64) {
        #pragma unroll
        for (int p = 0; p < 2; ++p) {
            int r0 = p * 32 + wv * 8;
            int row = r0 + (l >> 3);
            int gs = (l & 7) ^ (row & 7);
            gl_lds16(rotT + hbase + (long)(u0 + row) * 1024 + gs * 8, Ks + r0 * 64);
        }
        #pragma unroll
        for (int rep = 0; rep < 2; ++rep) {
            int ch = rep * 4 + wv;
            union { uint4 v; ushortT h8[8]; } tmp;
            tmp.v = *(const uint4*)(yT + hbase + (long)(u0 + l) * 1024 + ch * 8);
            #pragma unroll
            for (int j = 0; j < 8; ++j)
                Vs[(ch * 8 + j) * 72 + l] = tmp.h8[j];
        }
        __syncthreads();

        f32x4 sacc[4] = {};
        #pragma unroll
        for (int ko = 0; ko < 2; ++ko) {
            int ar = wv * 16 + lr;
            bf16x8 aq = *(const bf16x8*)&Qs[ar * 64 + (((ko * 4) + lk) ^ (ar & 7)) * 8];
            #pragma unroll
            for (int f = 0; f < 4; ++f) {
                int br = f * 16 + lr;
                bf16x8 bk = *(const bf16x8*)&Ks[br * 64 + (((ko * 4) + lk) ^ (br & 7)) * 8];
                sacc[f] = __builtin_amdgcn_mfma_f32_16x16x32_bf16(aq, bk, sacc[f], 0, 0, 0);
            }
        }

        #pragma unroll
        for (int rg = 0; rg < 4; ++rg) {
            float s0 = sacc[0][rg] * (1.f / 32.f);
            float s1 = sacc[1][rg] * (1.f / 32.f);
            float s2 = sacc[2][rg] * (1.f / 32.f);
            float s3 = sacc[3][rg] * (1.f / 32.f);
            float mx = fmaxf(fmaxf(s0, s1), fmaxf(s2, s3));
            mx = fmaxf(mx, __shfl_xor(mx, 1));
            mx = fmaxf(mx, __shfl_xor(mx, 2));
            mx = fmaxf(mx, __shfl_xor(mx, 4));
            mx = fmaxf(mx, __shfl_xor(mx, 8));
            float mnew = fmaxf(mrow[rg], mx);
            float al = __expf(mrow[rg] - mnew);
            float p0 = __expf(s0 - mnew), p1 = __expf(s1 - mnew);
            float p2 = __expf(s2 - mnew), p3 = __expf(s3 - mnew);
            float rs = p0 + p1 + p2 + p3;
            rs += __shfl_xor(rs, 1);
            rs += __shfl_xor(rs, 2);
            rs += __shfl_xor(rs, 4);
            rs += __shfl_xor(rs, 8);
            lrow[rg] = lrow[rg] * al + rs;
            mrow[rg] = mnew;
            oacc[0][rg] *= al; oacc[1][rg] *= al;
            oacc[2][rg] *= al; oacc[3][rg] *= al;
            int prow = wv * 16 + lk * 4 + rg;
            Ps[prow * 72 +  0 + lr] = f2bf(p0);
            Ps[prow * 72 + 16 + lr] = f2bf(p1);
            Ps[prow * 72 + 32 + lr] = f2bf(p2);
            Ps[prow * 72 + 48 + lr] = f2bf(p3);
        }
        asm volatile("s_waitcnt lgkmcnt(0)" ::: "memory");

        #pragma unroll
        for (int ko = 0; ko < 2; ++ko) {
            int ar = wv * 16 + lr;
            bf16x8 ap = *(const bf16x8*)&Ps[ar * 72 + ko * 32 + lk * 8];
            #pragma unroll
            for (int f = 0; f < 4; ++f) {
                bf16x8 bv = *(const bf16x8*)&Vs[(f * 16 + lr) * 72 + ko * 32 + lk * 8];
                oacc[f] = __builtin_amdgcn_mfma_f32_16x16x32_bf16(ap, bv, oacc[f], 0, 0, 0);
            }
        }
        __syncthreads();
    }

    #pragma unroll
    for (int rg = 0; rg < 4; ++rg) {
        float inv = 1.f / lrow[rg];
        int w = wq0 + wv * 16 + lk * 4 + rg;
        long b2 = (long)bc * WW * 1024 + (long)w * 1024 + h * 64;
        #pragma unroll
        for (int f = 0; f < 4; ++f)
            oT[b2 + f * 16 + lr] = f2bf(oacc[f][rg] * inv);
    }
}

// ---------------- fused-cast double-buffered MFMA GEMM ----------------
// C[z][M][N] = A_f32[z%aMod][M][K] @ B_bf16[z][N][K]^T
// A: fp32 weights, reg-staged + cast to bf16 into LDS. B: bf16, global_load_lds.
// 1D grid, XCD-chunked: lid = (bid&7)*(nwg/8) + bid>>3; lid -> (z,y,x).
template<bool HASRES, bool GELUF, bool TRANSOUT>
__global__ __launch_bounds__(256)
void fgemm_k(const float* __restrict__ A, long sA, int aMod,
             const ushortT* __restrict__ B, long sB,
             void* __restrict__ Cp, long sC,
             const float* __restrict__ R, long sR,
             int M, int N, int K, int gx, int gy)
{
    __shared__ ushortT smem[4 * 8192];   // [buf][As|Bs] 64KB
    const int nwg = gridDim.x;
    const int bid = blockIdx.x;
    const int lid = (bid & 7) * (nwg >> 3) + (bid >> 3);
    const int x = lid % gx;
    const int y = (lid / gx) % gy;
    const int z = lid / (gx * gy);
    const float*   Ab = A + (long)(z % aMod) * sA + (long)y * 128 * K;
    const ushortT* Bb = B + (long)z * sB + (long)x * 128 * K;
    const int tid = threadIdx.x;
    const int wv = tid >> 6, l = tid & 63;
    const int lrow = l & 15, lk = l >> 4;
    const int mb = (wv >> 1) * 64, nb = (wv & 1) * 64;
    // A-fetch cells: 4 per thread, cell=(row,grp): row=idx>>3, grp=idx&7
    const int ar0 = tid >> 3 << 0;  // base row for c=0 is idx>>3
    f32x4 acc[4][4] = {};
    float4 a0[4], a1[4];

    const int NT = K >> 6;

    // ---- helpers as lambdas ----
    auto fetchA = [&](int k0) {
        #pragma unroll
        for (int c = 0; c < 4; ++c) {
            int idx = tid + c * 256;
            int row = idx >> 3, grp = idx & 7;
            const float* src = Ab + (long)row * K + k0 + grp * 8;
            a0[c] = *(const float4*)src;
            a1[c] = *(const float4*)(src + 4);
        }
    };
    auto commitA = [&](int buf) {
        ushortT* AsB = smem + buf * 16384;
        #pragma unroll
        for (int c = 0; c < 4; ++c) {
            int idx = tid + c * 256;
            int row = idx >> 3, grp = idx & 7;
            union { ushortT h[8]; uint4 v; } r;
            r.h[0] = f2bf(a0[c].x); r.h[1] = f2bf(a0[c].y);
            r.h[2] = f2bf(a0[c].z); r.h[3] = f2bf(a0[c].w);
            r.h[4] = f2bf(a1[c].x); r.h[5] = f2bf(a1[c].y);
            r.h[6] = f2bf(a1[c].z); r.h[7] = f2bf(a1[c].w);
            *(uint4*)&AsB[row * 64 + ((grp ^ (row & 7)) << 3)] = r.v;
        }
    };
    auto stageB = [&](int buf, int k0) {
        ushortT* BsB = smem + 8192 + buf * 16384;
        #pragma unroll
        for (int t = 0; t < 4; ++t) {
            int r0 = wv * 32 + t * 8;
            int row = r0 + (l >> 3);
            int gs = (l & 7) ^ (row & 7);
            gl_lds16(Bb + (long)row * K + k0 + gs * 8, BsB + r0 * 64);
        }
    };
    auto compute = [&](int buf) {
        const ushortT* AsB = smem + buf * 16384;
        const ushortT* BsB = smem + 8192 + buf * 16384;
        #pragma unroll
        for (int ko = 0; ko < 2; ++ko) {
            bf16x8 af[4], bg[4];
            #pragma unroll
            for (int i = 0; i < 4; ++i) {
                int ra = mb + i * 16 + lrow;
                af[i] = *(const bf16x8*)&AsB[ra * 64 + ((lk + ko * 4) ^ (ra & 7)) * 8];
                int rb = nb + i * 16 + lrow;
                bg[i] = *(const bf16x8*)&BsB[rb * 64 + ((lk + ko * 4) ^ (rb & 7)) * 8];
            }
            #pragma unroll
            for (int i = 0; i < 4; ++i)
                #pragma unroll
                for (int j = 0; j < 4; ++j)
                    acc[i][j] = __builtin_amdgcn_mfma_f32_16x16x32_bf16(
                        af[i], bg[j], acc[i][j], 0, 0, 0);
        }
    };

    // prologue
    fetchA(0);
    stageB(0, 0);
    commitA(0);
    asm volatile("s_waitcnt vmcnt(0) lgkmcnt(0)" ::: "memory");
    __syncthreads();

    for (int t = 0; t < NT; ++t) {
        int buf = t & 1;
        if (t + 1 < NT) { fetchA((t + 1) << 6); stageB(buf ^ 1, (t + 1) << 6); }
        compute(buf);
        if (t + 1 < NT) {
            commitA(buf ^ 1);
            asm volatile("s_waitcnt vmcnt(0) lgkmcnt(0)" ::: "memory");
        }
        __syncthreads();
    }

    const int m0g = y * 128 + mb, n0g = x * 128 + nb;
    if (!TRANSOUT) {
        float* Cf = (float*)Cp + (long)z * sC;
        #pragma unroll
        for (int i = 0; i < 4; ++i)
            #pragma unroll
            for (int j = 0; j < 4; ++j)
                #pragma unroll
                for (int rg = 0; rg < 4; ++rg) {
                    long m = m0g + i * 16 + lk * 4 + rg;
                    long n = n0g + j * 16 + lrow;
                    float v = acc[i][j][rg];
                    if (GELUF) v = geluf(v);
                    if (HASRES) v += R[(long)z * sR + m * N + n];
                    Cf[m * N + n] = v;
                }
    } else {
        ushortT* Ts = smem + wv * 4096;
        __syncthreads();
        #pragma unroll
        for (int i = 0; i < 4; ++i)
            #pragma unroll
            for (int j = 0; j < 4; ++j)
                #pragma unroll
                for (int rg = 0; rg < 4; ++rg) {
                    int ml = i * 16 + lk * 4 + rg;
                    int nl = j * 16 + lrow;
                    float v = acc[i][j][rg];
                    if (GELUF) v = geluf(v);
                    Ts[nl * 64 + (((ml >> 3) ^ (nl & 7)) << 3) + (ml & 7)] = f2bf(v);
                }
        __syncthreads();
        ushortT* CT = (ushortT*)Cp + (long)z * sC;
        #pragma unroll
        for (int p = 0; p < 8; ++p) {
            int nl = p * 8 + (l >> 3), mc = l & 7;
            uint4 d = *(const uint4*)&Ts[nl * 64 + ((mc ^ (nl & 7)) << 3)];
            *(uint4*)&CT[(long)(n0g + nl) * M + m0g + mc * 8] = d;
        }
    }
}

extern "C" void kernel_launch(void* const* d_in, const int* in_sizes, int n_in,
                              void* d_out, int out_size, void* d_ws, size_t ws_size,
                              hipStream_t stream)
{
    const float* x    = (const float*)d_in[0];
    const float* n1w  = (const float*)d_in[1];
    const float* n1b  = (const float*)d_in[2];
    const float* freqs= (const float*)d_in[3];
    const float* qw   = (const float*)d_in[4];
    const float* ow   = (const float*)d_in[5];
    const float* n2w  = (const float*)d_in[6];
    const float* n2b  = (const float*)d_in[7];
    const float* l1w  = (const float*)d_in[8];
    const float* l2w  = (const float*)d_in[9];
    float* out = (float*)d_out;
    char* wsb  = (char*)d_ws;
    const long MB = 1L << 20;

    ushortT* znT  = (ushortT*)(wsb +   0 * MB);   // 16MB
    ushortT* yT   = (ushortT*)(wsb +  16 * MB);   // 16MB
    ushortT* rotT = (ushortT*)(wsb +  32 * MB);   // 16MB
    ushortT* CfT  = (ushortT*)(wsb +  48 * MB);   // 16MB
    ushortT* zn2T = (ushortT*)(wsb +  64 * MB);   // 16MB
    ushortT* h1T  = (ushortT*)(wsb +  80 * MB);   // 64MB
    float*   cosT = (float*)  (wsb + 144 * MB);
    float*   sinT = cosT + WW * 16;

    rope_tab_k<<<32, 256, 0, stream>>>(freqs, cosT, sinT);

    // norm1: x -> znT (bf16 [w][f])
    normT_k<<<BB * CCH * 16, 1024, 0, stream>>>(x, n1w, n1b, znT);

    // qproj (fp32 weights direct), transposed bf16 out: yT[bc][w][g]
    fgemm_k<false, false, true><<<512, 256, 0, stream>>>(
        qw,  (long)BINS * BINS, CCH,
        znT, (long)WW * BINS,
        yT,  (long)WW * BINS,
        nullptr, 0, BINS, WW, BINS, 4, 8);

    // rope: yT -> rotT (bf16)
    ropeB_k<<<4096, 256, 0, stream>>>(yT, cosT, sinT, rotT);

    // MFMA flash attention -> CfT [bc][w][g]
    mattn_k<<<dim3(8, 256), 256, 0, stream>>>(rotT, yT, CfT);

    // outproj + residual: out = x + ow[c] @ CfT^T
    fgemm_k<true, false, false><<<512, 256, 0, stream>>>(
        ow,  (long)BINS * BINS, CCH,
        CfT, (long)WW * BINS,
        out, (long)BINS * WW,
        x,   (long)BINS * WW, BINS, WW, BINS, 4, 8);

    // norm2: out -> zn2T (bf16 [w][f])
    normT_k<<<BB * CCH * 16, 1024, 0, stream>>>(out, n2w, n2b, zn2T);

    // lin1 + GELU, transposed bf16 out: h1T [w][4096]
    fgemm_k<false, true, true><<<2048, 256, 0, stream>>>(
        l1w,  (long)BINS * EXPF * BINS, CCH,
        zn2T, (long)WW * BINS,
        h1T,  (long)WW * BINS * EXPF,
        nullptr, 0, BINS * EXPF, WW, BINS, 4, 32);

    // lin2 + residual (in-place on out)
    fgemm_k<true, false, false><<<512, 256, 0, stream>>>(
        l2w, (long)BINS * BINS * EXPF, CCH,
        h1T, (long)WW * BINS * EXPF,
        out, (long)BINS * WW,
        out, (long)BINS * WW, BINS, WW, BINS * EXPF, 4, 8);
}

// Round 7
// 436.360 us; speedup vs baseline: 7.5018x; 1.0489x over previous
//
#include <hip/hip_runtime.h>
#include <math.h>

#define BB 2
#define CCH 8
#define BINS 1024
#define WW 512
#define HEADS 16
#define HD 64
#define ROTD 32
#define EXPF 4
#define NXE 8388608L   // B*C*BINS*W
#define NTW 32         // w-columns per norm block

typedef unsigned short ushortT;
typedef short bf16x8 __attribute__((ext_vector_type(8)));
typedef float f32x4 __attribute__((ext_vector_type(4)));

__device__ __forceinline__ ushortT f2bf(float f) {
    unsigned int u = __float_as_uint(f);
    u = (u + 0x7FFF + ((u >> 16) & 1)) >> 16;
    return (ushortT)u;
}
__device__ __forceinline__ float bf2f(ushortT h) {
    return __uint_as_float(((unsigned int)h) << 16);
}
__device__ __forceinline__ float geluf(float x) {
    return 0.5f * x * (1.f + erff(x * 0.70710678118654752f));
}
__device__ __forceinline__ void gl_lds16(const ushortT* g, ushortT* l) {
    __builtin_amdgcn_global_load_lds(
        (const __attribute__((address_space(1))) unsigned int*)g,
        (__attribute__((address_space(3))) unsigned int*)l, 16, 0, 0);
}

// ---------------- frame norm over BINS, transposed bf16 out [w][f] ----------------
__global__ __launch_bounds__(1024)
void normT_k(const float* __restrict__ X, const float* __restrict__ wgt,
             const float* __restrict__ bia, ushortT* __restrict__ YT)
{
    __shared__ float tile[NTW][BINS + 1];
    __shared__ float red0[32][NTW], red1[32][NTW];
    __shared__ float ms[NTW], is[NTW];
    const int bc = blockIdx.x >> 4;
    const int w0 = (blockIdx.x & 15) * NTW;
    const int tid = threadIdx.x;
    const int w  = tid & (NTW - 1);
    const int fy = tid >> 5;
    const float* Xb = X + (long)bc * BINS * WW + w0;
    float s = 0.f, s2 = 0.f;
    for (int f = fy; f < BINS; f += 32) {
        float v = Xb[(long)f * WW + w];
        s += v; s2 += v * v;
        tile[w][f] = v;
    }
    red0[fy][w] = s; red1[fy][w] = s2;
    __syncthreads();
    if (tid < NTW) {
        float ss = 0.f, qq = 0.f;
        #pragma unroll
        for (int j = 0; j < 32; ++j) { ss += red0[j][tid]; qq += red1[j][tid]; }
        float m = ss * (1.f / BINS);
        float var = qq * (1.f / BINS) - m * m;
        ms[tid] = m; is[tid] = rsqrtf(var + 1e-5f);
    }
    __syncthreads();
    const int w2 = tid >> 5;
    const int c  = tid & 31;
    float m = ms[w2], inv = is[w2];
    ushortT* Yb = YT + ((long)bc * WW + w0 + w2) * BINS;
    #pragma unroll
    for (int jj = 0; jj < 4; ++jj) {
        int f0 = jj * 256 + c * 8;
        union { ushortT h[8]; uint4 v; } r;
        #pragma unroll
        for (int e = 0; e < 8; ++e) {
            int f = f0 + e;
            float v = (tile[w2][f] - m) * inv * wgt[f] + bia[f];
            r.h[e] = f2bf(v);
        }
        *(uint4*)&Yb[f0] = r.v;
    }
}

// ---------------- RoPE tables ----------------
__global__ void rope_tab_k(const float* __restrict__ freqs,
                           float* __restrict__ cosT, float* __restrict__ sinT)
{
    int idx = blockIdx.x * 256 + threadIdx.x;
    if (idx >= WW * 16) return;
    int w = idx >> 4, i = idx & 15;
    float ang = (float)w * freqs[i];
    cosT[idx] = cosf(ang);
    sinT[idx] = sinf(ang);
}

// ---------------- RoPE on bf16 [w][g] layout ----------------
__global__ __launch_bounds__(256)
void ropeB_k(const ushortT* __restrict__ yT, const float* __restrict__ cosT,
             const float* __restrict__ sinT, ushortT* __restrict__ rotT)
{
    long e0 = ((long)blockIdx.x * 256 + threadIdx.x) * 8;
    if (e0 >= NXE) return;
    int g0 = (int)(e0 & 1023);
    int w  = (int)((e0 >> 10) & 511);
    int d0 = g0 & 63;
    union { uint4 v; ushortT h8[8]; } in, ov;
    in.v = *(const uint4*)&yT[e0];
    if (d0 >= ROTD) {
        *(uint4*)&rotT[e0] = in.v;
        return;
    }
    #pragma unroll
    for (int j = 0; j < 8; j += 2) {
        int i = (d0 + j) >> 1;
        float c = cosT[w * 16 + i], s = sinT[w * 16 + i];
        float a = bf2f(in.h8[j]), b = bf2f(in.h8[j + 1]);
        ov.h8[j]     = f2bf(a * c - b * s);
        ov.h8[j + 1] = f2bf(b * c + a * s);
    }
    *(uint4*)&rotT[e0] = ov.v;
}

// ---------------- MFMA flash attention ----------------
__global__ __launch_bounds__(256)
void mattn_k(const ushortT* __restrict__ rotT, const ushortT* __restrict__ yT,
             ushortT* __restrict__ oT)
{
    __shared__ ushortT Qs[64 * 64];
    __shared__ ushortT Ks[64 * 64];
    __shared__ ushortT Vs[64 * 72];
    __shared__ ushortT Ps[64 * 72];
    const int z = blockIdx.y;
    const int bc = z >> 4, h = z & 15;
    const int wq0 = blockIdx.x * 64;
    const int tid = threadIdx.x;
    const int wv = tid >> 6, l = tid & 63;
    const int lr = l & 15, lk = l >> 4;
    const long hbase = (long)bc * WW * 1024 + h * 64;

    #pragma unroll
    for (int p = 0; p < 2; ++p) {
        int r0 = p * 32 + wv * 8;
        int row = r0 + (l >> 3);
        int gs = (l & 7) ^ (row & 7);
        gl_lds16(rotT + hbase + (long)(wq0 + row) * 1024 + gs * 8, Qs + r0 * 64);
    }

    f32x4 oacc[4] = {};
    float mrow[4] = {-INFINITY, -INFINITY, -INFINITY, -INFINITY};
    float lrow[4] = {0.f, 0.f, 0.f, 0.f};

    for (int u0 = 0; u0 < WW; u0 += 64) {
        #pragma unroll
        for (int p = 0; p < 2; ++p) {
            int r0 = p * 32 + wv * 8;
            int row = r0 + (l >> 3);
            int gs = (l & 7) ^ (row & 7);
            gl_lds16(rotT + hbase + (long)(u0 + row) * 1024 + gs * 8, Ks + r0 * 64);
        }
        #pragma unroll
        for (int rep = 0; rep < 2; ++rep) {
            int ch = rep * 4 + wv;
            union { uint4 v; ushortT h8[8]; } tmp;
            tmp.v = *(const uint4*)(yT + hbase + (long)(u0 + l) * 1024 + ch * 8);
            #pragma unroll
            for (int j = 0; j < 8; ++j)
                Vs[(ch * 8 + j) * 72 + l] = tmp.h8[j];
        }
        __syncthreads();

        f32x4 sacc[4] = {};
        #pragma unroll
        for (int ko = 0; ko < 2; ++ko) {
            int ar = wv * 16 + lr;
            bf16x8 aq = *(const bf16x8*)&Qs[ar * 64 + (((ko * 4) + lk) ^ (ar & 7)) * 8];
            #pragma unroll
            for (int f = 0; f < 4; ++f) {
                int br = f * 16 + lr;
                bf16x8 bk = *(const bf16x8*)&Ks[br * 64 + (((ko * 4) + lk) ^ (br & 7)) * 8];
                sacc[f] = __builtin_amdgcn_mfma_f32_16x16x32_bf16(aq, bk, sacc[f], 0, 0, 0);
            }
        }

        #pragma unroll
        for (int rg = 0; rg < 4; ++rg) {
            float s0 = sacc[0][rg] * (1.f / 32.f);
            float s1 = sacc[1][rg] * (1.f / 32.f);
            float s2 = sacc[2][rg] * (1.f / 32.f);
            float s3 = sacc[3][rg] * (1.f / 32.f);
            float mx = fmaxf(fmaxf(s0, s1), fmaxf(s2, s3));
            mx = fmaxf(mx, __shfl_xor(mx, 1));
            mx = fmaxf(mx, __shfl_xor(mx, 2));
            mx = fmaxf(mx, __shfl_xor(mx, 4));
            mx = fmaxf(mx, __shfl_xor(mx, 8));
            float mnew = fmaxf(mrow[rg], mx);
            float al = __expf(mrow[rg] - mnew);
            float p0 = __expf(s0 - mnew), p1 = __expf(s1 - mnew);
            float p2 = __expf(s2 - mnew), p3 = __expf(s3 - mnew);
            float rs = p0 + p1 + p2 + p3;
            rs += __shfl_xor(rs, 1);
            rs += __shfl_xor(rs, 2);
            rs += __shfl_xor(rs, 4);
            rs += __shfl_xor(rs, 8);
            lrow[rg] = lrow[rg] * al + rs;
            mrow[rg] = mnew;
            oacc[0][rg] *= al; oacc[1][rg] *= al;
            oacc[2][rg] *= al; oacc[3][rg] *= al;
            int prow = wv * 16 + lk * 4 + rg;
            Ps[prow * 72 +  0 + lr] = f2bf(p0);
            Ps[prow * 72 + 16 + lr] = f2bf(p1);
            Ps[prow * 72 + 32 + lr] = f2bf(p2);
            Ps[prow * 72 + 48 + lr] = f2bf(p3);
        }
        asm volatile("s_waitcnt lgkmcnt(0)" ::: "memory");

        #pragma unroll
        for (int ko = 0; ko < 2; ++ko) {
            int ar = wv * 16 + lr;
            bf16x8 ap = *(const bf16x8*)&Ps[ar * 72 + ko * 32 + lk * 8];
            #pragma unroll
            for (int f = 0; f < 4; ++f) {
                bf16x8 bv = *(const bf16x8*)&Vs[(f * 16 + lr) * 72 + ko * 32 + lk * 8];
                oacc[f] = __builtin_amdgcn_mfma_f32_16x16x32_bf16(ap, bv, oacc[f], 0, 0, 0);
            }
        }
        __syncthreads();
    }

    #pragma unroll
    for (int rg = 0; rg < 4; ++rg) {
        float inv = 1.f / lrow[rg];
        int w = wq0 + wv * 16 + lk * 4 + rg;
        long b2 = (long)bc * WW * 1024 + (long)w * 1024 + h * 64;
        #pragma unroll
        for (int f = 0; f < 4; ++f)
            oT[b2 + f * 16 + lr] = f2bf(oacc[f][rg] * inv);
    }
}

// ---------------- fused-cast single-buffer MFMA GEMM, counted-vmcnt pipeline ----------------
// C[z][M][N] = A_f32[z%aMod][M][K] @ B_bf16[z][N][K]^T
// A: fp32 weights reg-fetched (prefetch t+1 under compute t), cast->bf16->LDS.
// B: bf16 via global_load_lds. 32KB LDS total. XCD-chunked 1D grid.
template<bool HASRES, bool GELUF, bool TRANSOUT>
__global__ __launch_bounds__(256)
void fgemm_k(const float* __restrict__ A, long sA, int aMod,
             const ushortT* __restrict__ B, long sB,
             void* __restrict__ Cp, long sC,
             const float* __restrict__ R, long sR,
             int M, int N, int K, int gx, int gy)
{
    __shared__ ushortT smem[2 * 8192];   // As | Bs  (32 KB)
    ushortT* As = smem;
    ushortT* Bs = smem + 8192;
    const int nwg = gridDim.x;
    const int bid = blockIdx.x;
    const int lid = (bid & 7) * (nwg >> 3) + (bid >> 3);
    const int x = lid % gx;
    const int y = (lid / gx) % gy;
    const int z = lid / (gx * gy);
    const float*   Ab = A + (long)(z % aMod) * sA + (long)y * 128 * K;
    const ushortT* Bb = B + (long)z * sB + (long)x * 128 * K;
    const int tid = threadIdx.x;
    const int wv = tid >> 6, l = tid & 63;
    const int lrow = l & 15, lk = l >> 4;
    const int mb = (wv >> 1) * 64, nb = (wv & 1) * 64;
    const int arow = tid >> 3, agrp = tid & 7;
    f32x4 acc[4][4] = {};
    float4 a0[4], a1[4];
    const int NT = K >> 6;

    auto fetchA = [&](int k0) {
        #pragma unroll
        for (int c = 0; c < 4; ++c) {
            const float* src = Ab + (long)(arow + c * 32) * K + k0 + agrp * 8;
            a0[c] = *(const float4*)src;
            a1[c] = *(const float4*)(src + 4);
        }
    };
    auto commitA = [&]() {
        #pragma unroll
        for (int c = 0; c < 4; ++c) {
            int row = arow + c * 32;
            union { ushortT h[8]; uint4 v; } r;
            r.h[0] = f2bf(a0[c].x); r.h[1] = f2bf(a0[c].y);
            r.h[2] = f2bf(a0[c].z); r.h[3] = f2bf(a0[c].w);
            r.h[4] = f2bf(a1[c].x); r.h[5] = f2bf(a1[c].y);
            r.h[6] = f2bf(a1[c].z); r.h[7] = f2bf(a1[c].w);
            *(uint4*)&As[row * 64 + ((agrp ^ (row & 7)) << 3)] = r.v;
        }
    };
    auto stageB = [&](int k0) {
        #pragma unroll
        for (int t = 0; t < 4; ++t) {
            int r0 = wv * 32 + t * 8;
            int row = r0 + (l >> 3);
            int gs = (l & 7) ^ (row & 7);
            gl_lds16(Bb + (long)row * K + k0 + gs * 8, Bs + r0 * 64);
        }
    };
    auto compute = [&]() {
        #pragma unroll
        for (int ko = 0; ko < 2; ++ko) {
            bf16x8 af[4], bg[4];
            #pragma unroll
            for (int i = 0; i < 4; ++i) {
                int ra = mb + i * 16 + lrow;
                af[i] = *(const bf16x8*)&As[ra * 64 + ((lk + ko * 4) ^ (ra & 7)) * 8];
                int rb = nb + i * 16 + lrow;
                bg[i] = *(const bf16x8*)&Bs[rb * 64 + ((lk + ko * 4) ^ (rb & 7)) * 8];
            }
            #pragma unroll
            for (int i = 0; i < 4; ++i)
                #pragma unroll
                for (int j = 0; j < 4; ++j)
                    acc[i][j] = __builtin_amdgcn_mfma_f32_16x16x32_bf16(
                        af[i], bg[j], acc[i][j], 0, 0, 0);
        }
    };

    fetchA(0);
    for (int t = 0; t < NT; ++t) {
        __builtin_amdgcn_s_barrier();            // prev tile fully consumed
        __builtin_amdgcn_sched_barrier(0);
        stageB(t << 6);                           // 4 gl_lds (oldest in vm queue)
        __builtin_amdgcn_sched_barrier(0);
        commitA();                                // ds_write A(t) from regs
        if (t + 1 < NT) {
            fetchA((t + 1) << 6);                 // 8 reg loads (younger)
            __builtin_amdgcn_sched_barrier(0);
            asm volatile("s_waitcnt vmcnt(8) lgkmcnt(0)" ::: "memory");
        } else {
            __builtin_amdgcn_sched_barrier(0);
            asm volatile("s_waitcnt vmcnt(0) lgkmcnt(0)" ::: "memory");
        }
        __builtin_amdgcn_s_barrier();            // tile t staged for all waves
        __builtin_amdgcn_sched_barrier(0);
        compute();
    }

    const int m0g = y * 128 + mb, n0g = x * 128 + nb;
    if (!TRANSOUT) {
        float* Cf = (float*)Cp + (long)z * sC;
        #pragma unroll
        for (int i = 0; i < 4; ++i)
            #pragma unroll
            for (int j = 0; j < 4; ++j)
                #pragma unroll
                for (int rg = 0; rg < 4; ++rg) {
                    long m = m0g + i * 16 + lk * 4 + rg;
                    long n = n0g + j * 16 + lrow;
                    float v = acc[i][j][rg];
                    if (GELUF) v = geluf(v);
                    if (HASRES) v += R[(long)z * sR + m * N + n];
                    Cf[m * N + n] = v;
                }
    } else {
        ushortT* Ts = smem + wv * 4096;
        __syncthreads();
        #pragma unroll
        for (int i = 0; i < 4; ++i)
            #pragma unroll
            for (int j = 0; j < 4; ++j)
                #pragma unroll
                for (int rg = 0; rg < 4; ++rg) {
                    int ml = i * 16 + lk * 4 + rg;
                    int nl = j * 16 + lrow;
                    float v = acc[i][j][rg];
                    if (GELUF) v = geluf(v);
                    Ts[nl * 64 + (((ml >> 3) ^ (nl & 7)) << 3) + (ml & 7)] = f2bf(v);
                }
        __syncthreads();
        ushortT* CT = (ushortT*)Cp + (long)z * sC;
        #pragma unroll
        for (int p = 0; p < 8; ++p) {
            int nl = p * 8 + (l >> 3), mc = l & 7;
            uint4 d = *(const uint4*)&Ts[nl * 64 + ((mc ^ (nl & 7)) << 3)];
            *(uint4*)&CT[(long)(n0g + nl) * M + m0g + mc * 8] = d;
        }
    }
}

extern "C" void kernel_launch(void* const* d_in, const int* in_sizes, int n_in,
                              void* d_out, int out_size, void* d_ws, size_t ws_size,
                              hipStream_t stream)
{
    const float* x    = (const float*)d_in[0];
    const float* n1w  = (const float*)d_in[1];
    const float* n1b  = (const float*)d_in[2];
    const float* freqs= (const float*)d_in[3];
    const float* qw   = (const float*)d_in[4];
    const float* ow   = (const float*)d_in[5];
    const float* n2w  = (const float*)d_in[6];
    const float* n2b  = (const float*)d_in[7];
    const float* l1w  = (const float*)d_in[8];
    const float* l2w  = (const float*)d_in[9];
    float* out = (float*)d_out;
    char* wsb  = (char*)d_ws;
    const long MB = 1L << 20;

    ushortT* znT  = (ushortT*)(wsb +   0 * MB);   // 16MB
    ushortT* yT   = (ushortT*)(wsb +  16 * MB);   // 16MB
    ushortT* rotT = (ushortT*)(wsb +  32 * MB);   // 16MB
    ushortT* CfT  = (ushortT*)(wsb +  48 * MB);   // 16MB
    ushortT* zn2T = (ushortT*)(wsb +  64 * MB);   // 16MB
    ushortT* h1T  = (ushortT*)(wsb +  80 * MB);   // 64MB
    float*   cosT = (float*)  (wsb + 144 * MB);
    float*   sinT = cosT + WW * 16;

    rope_tab_k<<<32, 256, 0, stream>>>(freqs, cosT, sinT);

    // norm1: x -> znT (bf16 [w][f])
    normT_k<<<BB * CCH * 16, 1024, 0, stream>>>(x, n1w, n1b, znT);

    // qproj (fp32 weights direct), transposed bf16 out: yT[bc][w][g]
    fgemm_k<false, false, true><<<512, 256, 0, stream>>>(
        qw,  (long)BINS * BINS, CCH,
        znT, (long)WW * BINS,
        yT,  (long)WW * BINS,
        nullptr, 0, BINS, WW, BINS, 4, 8);

    // rope: yT -> rotT (bf16)
    ropeB_k<<<4096, 256, 0, stream>>>(yT, cosT, sinT, rotT);

    // MFMA flash attention -> CfT [bc][w][g]
    mattn_k<<<dim3(8, 256), 256, 0, stream>>>(rotT, yT, CfT);

    // outproj + residual: out = x + ow[c] @ CfT^T
    fgemm_k<true, false, false><<<512, 256, 0, stream>>>(
        ow,  (long)BINS * BINS, CCH,
        CfT, (long)WW * BINS,
        out, (long)BINS * WW,
        x,   (long)BINS * WW, BINS, WW, BINS, 4, 8);

    // norm2: out -> zn2T (bf16 [w][f])
    normT_k<<<BB * CCH * 16, 1024, 0, stream>>>(out, n2w, n2b, zn2T);

    // lin1 + GELU, transposed bf16 out: h1T [w][4096]
    fgemm_k<false, true, true><<<2048, 256, 0, stream>>>(
        l1w,  (long)BINS * EXPF * BINS, CCH,
        zn2T, (long)WW * BINS,
        h1T,  (long)WW * BINS * EXPF,
        nullptr, 0, BINS * EXPF, WW, BINS, 4, 32);

    // lin2 + residual (in-place on out)
    fgemm_k<true, false, false><<<512, 256, 0, stream>>>(
        l2w, (long)BINS * BINS * EXPF, CCH,
        h1T, (long)WW * BINS * EXPF,
        out, (long)BINS * WW,
        out, (long)BINS * WW, BINS, WW, BINS * EXPF, 4, 8);
}

// Round 8
// 434.734 us; speedup vs baseline: 7.5299x; 1.0037x over previous
//
#include <hip/hip_runtime.h>
#include <math.h>

#define BB 2
#define CCH 8
#define BINS 1024
#define WW 512
#define HEADS 16
#define HD 64
#define ROTD 32
#define EXPF 4
#define NXE 8388608L   // B*C*BINS*W
#define NTW 32         // w-columns per norm block

typedef unsigned short ushortT;
typedef short bf16x8 __attribute__((ext_vector_type(8)));
typedef float f32x4 __attribute__((ext_vector_type(4)));

__device__ __forceinline__ ushortT f2bf(float f) {
    unsigned int u = __float_as_uint(f);
    u = (u + 0x7FFF + ((u >> 16) & 1)) >> 16;
    return (ushortT)u;
}
__device__ __forceinline__ float bf2f(ushortT h) {
    return __uint_as_float(((unsigned int)h) << 16);
}
__device__ __forceinline__ unsigned int cvtpk(float lo, float hi) {
    unsigned int r;
    asm("v_cvt_pk_bf16_f32 %0, %1, %2" : "=v"(r) : "v"(lo), "v"(hi));
    return r;
}
__device__ __forceinline__ float geluf(float x) {
    return 0.5f * x * (1.f + erff(x * 0.70710678118654752f));
}
__device__ __forceinline__ void gl_lds16(const ushortT* g, ushortT* l) {
    __builtin_amdgcn_global_load_lds(
        (const __attribute__((address_space(1))) unsigned int*)g,
        (__attribute__((address_space(3))) unsigned int*)l, 16, 0, 0);
}

// ---------------- frame norm over BINS, transposed bf16 out [w][f] ----------------
__global__ __launch_bounds__(1024)
void normT_k(const float* __restrict__ X, const float* __restrict__ wgt,
             const float* __restrict__ bia, ushortT* __restrict__ YT)
{
    __shared__ float tile[NTW][BINS + 1];
    __shared__ float red0[32][NTW], red1[32][NTW];
    __shared__ float ms[NTW], is[NTW];
    const int bc = blockIdx.x >> 4;
    const int w0 = (blockIdx.x & 15) * NTW;
    const int tid = threadIdx.x;
    const int w  = tid & (NTW - 1);
    const int fy = tid >> 5;
    const float* Xb = X + (long)bc * BINS * WW + w0;
    float s = 0.f, s2 = 0.f;
    for (int f = fy; f < BINS; f += 32) {
        float v = Xb[(long)f * WW + w];
        s += v; s2 += v * v;
        tile[w][f] = v;
    }
    red0[fy][w] = s; red1[fy][w] = s2;
    __syncthreads();
    if (tid < NTW) {
        float ss = 0.f, qq = 0.f;
        #pragma unroll
        for (int j = 0; j < 32; ++j) { ss += red0[j][tid]; qq += red1[j][tid]; }
        float m = ss * (1.f / BINS);
        float var = qq * (1.f / BINS) - m * m;
        ms[tid] = m; is[tid] = rsqrtf(var + 1e-5f);
    }
    __syncthreads();
    const int w2 = tid >> 5;
    const int c  = tid & 31;
    float m = ms[w2], inv = is[w2];
    ushortT* Yb = YT + ((long)bc * WW + w0 + w2) * BINS;
    #pragma unroll
    for (int jj = 0; jj < 4; ++jj) {
        int f0 = jj * 256 + c * 8;
        union { ushortT h[8]; uint4 v; } r;
        #pragma unroll
        for (int e = 0; e < 8; ++e) {
            int f = f0 + e;
            float v = (tile[w2][f] - m) * inv * wgt[f] + bia[f];
            r.h[e] = f2bf(v);
        }
        *(uint4*)&Yb[f0] = r.v;
    }
}

// ---------------- RoPE tables ----------------
__global__ void rope_tab_k(const float* __restrict__ freqs,
                           float* __restrict__ cosT, float* __restrict__ sinT)
{
    int idx = blockIdx.x * 256 + threadIdx.x;
    if (idx >= WW * 16) return;
    int w = idx >> 4, i = idx & 15;
    float ang = (float)w * freqs[i];
    cosT[idx] = cosf(ang);
    sinT[idx] = sinf(ang);
}

// ---------------- RoPE on bf16 [w][g] layout ----------------
__global__ __launch_bounds__(256)
void ropeB_k(const ushortT* __restrict__ yT, const float* __restrict__ cosT,
             const float* __restrict__ sinT, ushortT* __restrict__ rotT)
{
    long e0 = ((long)blockIdx.x * 256 + threadIdx.x) * 8;
    if (e0 >= NXE) return;
    int g0 = (int)(e0 & 1023);
    int w  = (int)((e0 >> 10) & 511);
    int d0 = g0 & 63;
    union { uint4 v; ushortT h8[8]; } in, ov;
    in.v = *(const uint4*)&yT[e0];
    if (d0 >= ROTD) {
        *(uint4*)&rotT[e0] = in.v;
        return;
    }
    #pragma unroll
    for (int j = 0; j < 8; j += 2) {
        int i = (d0 + j) >> 1;
        float c = cosT[w * 16 + i], s = sinT[w * 16 + i];
        float a = bf2f(in.h8[j]), b = bf2f(in.h8[j + 1]);
        ov.h8[j]     = f2bf(a * c - b * s);
        ov.h8[j + 1] = f2bf(b * c + a * s);
    }
    *(uint4*)&rotT[e0] = ov.v;
}

// ---------------- MFMA flash attention ----------------
__global__ __launch_bounds__(256)
void mattn_k(const ushortT* __restrict__ rotT, const ushortT* __restrict__ yT,
             ushortT* __restrict__ oT)
{
    __shared__ ushortT Qs[64 * 64];
    __shared__ ushortT Ks[64 * 64];
    __shared__ ushortT Vs[64 * 72];
    __shared__ ushortT Ps[64 * 72];
    const int z = blockIdx.y;
    const int bc = z >> 4, h = z & 15;
    const int wq0 = blockIdx.x * 64;
    const int tid = threadIdx.x;
    const int wv = tid >> 6, l = tid & 63;
    const int lr = l & 15, lk = l >> 4;
    const long hbase = (long)bc * WW * 1024 + h * 64;

    #pragma unroll
    for (int p = 0; p < 2; ++p) {
        int r0 = p * 32 + wv * 8;
        int row = r0 + (l >> 3);
        int gs = (l & 7) ^ (row & 7);
        gl_lds16(rotT + hbase + (long)(wq0 + row) * 1024 + gs * 8, Qs + r0 * 64);
    }

    f32x4 oacc[4] = {};
    float mrow[4] = {-INFINITY, -INFINITY, -INFINITY, -INFINITY};
    float lrow[4] = {0.f, 0.f, 0.f, 0.f};

    for (int u0 = 0; u0 < WW; u0 += 64) {
        #pragma unroll
        for (int p = 0; p < 2; ++p) {
            int r0 = p * 32 + wv * 8;
            int row = r0 + (l >> 3);
            int gs = (l & 7) ^ (row & 7);
            gl_lds16(rotT + hbase + (long)(u0 + row) * 1024 + gs * 8, Ks + r0 * 64);
        }
        #pragma unroll
        for (int rep = 0; rep < 2; ++rep) {
            int ch = rep * 4 + wv;
            union { uint4 v; ushortT h8[8]; } tmp;
            tmp.v = *(const uint4*)(yT + hbase + (long)(u0 + l) * 1024 + ch * 8);
            #pragma unroll
            for (int j = 0; j < 8; ++j)
                Vs[(ch * 8 + j) * 72 + l] = tmp.h8[j];
        }
        __syncthreads();

        f32x4 sacc[4] = {};
        #pragma unroll
        for (int ko = 0; ko < 2; ++ko) {
            int ar = wv * 16 + lr;
            bf16x8 aq = *(const bf16x8*)&Qs[ar * 64 + (((ko * 4) + lk) ^ (ar & 7)) * 8];
            #pragma unroll
            for (int f = 0; f < 4; ++f) {
                int br = f * 16 + lr;
                bf16x8 bk = *(const bf16x8*)&Ks[br * 64 + (((ko * 4) + lk) ^ (br & 7)) * 8];
                sacc[f] = __builtin_amdgcn_mfma_f32_16x16x32_bf16(aq, bk, sacc[f], 0, 0, 0);
            }
        }

        #pragma unroll
        for (int rg = 0; rg < 4; ++rg) {
            float s0 = sacc[0][rg] * (1.f / 32.f);
            float s1 = sacc[1][rg] * (1.f / 32.f);
            float s2 = sacc[2][rg] * (1.f / 32.f);
            float s3 = sacc[3][rg] * (1.f / 32.f);
            float mx = fmaxf(fmaxf(s0, s1), fmaxf(s2, s3));
            mx = fmaxf(mx, __shfl_xor(mx, 1));
            mx = fmaxf(mx, __shfl_xor(mx, 2));
            mx = fmaxf(mx, __shfl_xor(mx, 4));
            mx = fmaxf(mx, __shfl_xor(mx, 8));
            float mnew = fmaxf(mrow[rg], mx);
            float al = __expf(mrow[rg] - mnew);
            float p0 = __expf(s0 - mnew), p1 = __expf(s1 - mnew);
            float p2 = __expf(s2 - mnew), p3 = __expf(s3 - mnew);
            float rs = p0 + p1 + p2 + p3;
            rs += __shfl_xor(rs, 1);
            rs += __shfl_xor(rs, 2);
            rs += __shfl_xor(rs, 4);
            rs += __shfl_xor(rs, 8);
            lrow[rg] = lrow[rg] * al + rs;
            mrow[rg] = mnew;
            oacc[0][rg] *= al; oacc[1][rg] *= al;
            oacc[2][rg] *= al; oacc[3][rg] *= al;
            int prow = wv * 16 + lk * 4 + rg;
            Ps[prow * 72 +  0 + lr] = f2bf(p0);
            Ps[prow * 72 + 16 + lr] = f2bf(p1);
            Ps[prow * 72 + 32 + lr] = f2bf(p2);
            Ps[prow * 72 + 48 + lr] = f2bf(p3);
        }
        asm volatile("s_waitcnt lgkmcnt(0)" ::: "memory");

        #pragma unroll
        for (int ko = 0; ko < 2; ++ko) {
            int ar = wv * 16 + lr;
            bf16x8 ap = *(const bf16x8*)&Ps[ar * 72 + ko * 32 + lk * 8];
            #pragma unroll
            for (int f = 0; f < 4; ++f) {
                bf16x8 bv = *(const bf16x8*)&Vs[(f * 16 + lr) * 72 + ko * 32 + lk * 8];
                oacc[f] = __builtin_amdgcn_mfma_f32_16x16x32_bf16(ap, bv, oacc[f], 0, 0, 0);
            }
        }
        __syncthreads();
    }

    #pragma unroll
    for (int rg = 0; rg < 4; ++rg) {
        float inv = 1.f / lrow[rg];
        int w = wq0 + wv * 16 + lk * 4 + rg;
        long b2 = (long)bc * WW * 1024 + (long)w * 1024 + h * 64;
        #pragma unroll
        for (int f = 0; f < 4; ++f)
            oT[b2 + f * 16 + lr] = f2bf(oacc[f][rg] * inv);
    }
}

// ---------------- fused-cast MFMA GEMM, 2-deep counted-vmcnt pipeline ----------------
// C[z][M][N] = A_f32[z%aMod][M][K] @ B_bf16[z][N][K]^T
// A: fp32 weights reg-fetched 1 tile ahead, cvt_pk cast -> bf16 LDS (single buf).
// B: bf16 via global_load_lds, DOUBLE-buffered, 2 tiles in flight (vmcnt(12)).
// LDS 48KB (3 blocks/CU). XCD-chunked 1D grid.
template<bool HASRES, bool GELUF, bool TRANSOUT>
__global__ __launch_bounds__(256)
void fgemm_k(const float* __restrict__ A, long sA, int aMod,
             const ushortT* __restrict__ B, long sB,
             void* __restrict__ Cp, long sC,
             const float* __restrict__ R, long sR,
             int M, int N, int K, int gx, int gy)
{
    __shared__ ushortT smem[3 * 8192];   // As | Bs0 | Bs1  (48 KB)
    ushortT* As = smem;
    const int nwg = gridDim.x;
    const int bid = blockIdx.x;
    const int lid = (bid & 7) * (nwg >> 3) + (bid >> 3);
    const int x = lid % gx;
    const int y = (lid / gx) % gy;
    const int z = lid / (gx * gy);
    const float*   Ab = A + (long)(z % aMod) * sA + (long)y * 128 * K;
    const ushortT* Bb = B + (long)z * sB + (long)x * 128 * K;
    const int tid = threadIdx.x;
    const int wv = tid >> 6, l = tid & 63;
    const int lrow = l & 15, lk = l >> 4;
    const int mb = (wv >> 1) * 64, nb = (wv & 1) * 64;
    const int arow = tid >> 3, agrp = tid & 7;
    f32x4 acc[4][4] = {};
    float4 a0[4], a1[4];
    const int NT = K >> 6;

    auto fetchA = [&](int k0) {
        #pragma unroll
        for (int c = 0; c < 4; ++c) {
            const float* src = Ab + (long)(arow + c * 32) * K + k0 + agrp * 8;
            a0[c] = *(const float4*)src;
            a1[c] = *(const float4*)(src + 4);
        }
    };
    auto commitA = [&]() {
        #pragma unroll
        for (int c = 0; c < 4; ++c) {
            int row = arow + c * 32;
            uint4 v;
            v.x = cvtpk(a0[c].x, a0[c].y);
            v.y = cvtpk(a0[c].z, a0[c].w);
            v.z = cvtpk(a1[c].x, a1[c].y);
            v.w = cvtpk(a1[c].z, a1[c].w);
            *(uint4*)&As[row * 64 + ((agrp ^ (row & 7)) << 3)] = v;
        }
    };
    auto stageB = [&](int k0, int buf) {
        ushortT* BsB = smem + 8192 + buf * 8192;
        #pragma unroll
        for (int t = 0; t < 4; ++t) {
            int r0 = wv * 32 + t * 8;
            int row = r0 + (l >> 3);
            int gs = (l & 7) ^ (row & 7);
            gl_lds16(Bb + (long)row * K + k0 + gs * 8, BsB + r0 * 64);
        }
    };
    auto compute = [&](int buf) {
        const ushortT* BsB = smem + 8192 + buf * 8192;
        #pragma unroll
        for (int ko = 0; ko < 2; ++ko) {
            bf16x8 af[4], bg[4];
            #pragma unroll
            for (int i = 0; i < 4; ++i) {
                int ra = mb + i * 16 + lrow;
                af[i] = *(const bf16x8*)&As[ra * 64 + ((lk + ko * 4) ^ (ra & 7)) * 8];
                int rb = nb + i * 16 + lrow;
                bg[i] = *(const bf16x8*)&BsB[rb * 64 + ((lk + ko * 4) ^ (rb & 7)) * 8];
            }
            #pragma unroll
            for (int i = 0; i < 4; ++i)
                #pragma unroll
                for (int j = 0; j < 4; ++j)
                    acc[i][j] = __builtin_amdgcn_mfma_f32_16x16x32_bf16(
                        af[i], bg[j], acc[i][j], 0, 0, 0);
        }
    };

    // prologue: A(0) -> As; B(0) -> Bs0; A(1) regs + B(1) -> Bs1 left in flight
    fetchA(0);
    stageB(0, 0);
    commitA();
    if (NT > 1) {
        fetchA(64);
        stageB(64, 1);
        asm volatile("s_waitcnt vmcnt(12) lgkmcnt(0)" ::: "memory");
    } else {
        asm volatile("s_waitcnt vmcnt(0) lgkmcnt(0)" ::: "memory");
    }
    __builtin_amdgcn_s_barrier();

    for (int t = 0; t < NT; ++t) {
        compute(t & 1);
        __builtin_amdgcn_s_barrier();          // all waves done with As / Bs[t&1]
        if (t + 1 < NT) {
            commitA();                          // A(t+1) regs -> As (wait covered by compute)
            if (t + 2 < NT) {
                fetchA((t + 2) << 6);           // A(t+2): 8 loads
                stageB((t + 2) << 6, t & 1);    // B(t+2): 4 gl_lds into freed buffer
                asm volatile("s_waitcnt vmcnt(12) lgkmcnt(0)" ::: "memory");  // B(t+1) landed
            } else {
                asm volatile("s_waitcnt vmcnt(0) lgkmcnt(0)" ::: "memory");
            }
            __builtin_amdgcn_s_barrier();       // Bs[(t+1)&1] + As visible to all
        }
    }

    const int m0g = y * 128 + mb, n0g = x * 128 + nb;
    if (!TRANSOUT) {
        float* Cf = (float*)Cp + (long)z * sC;
        #pragma unroll
        for (int i = 0; i < 4; ++i)
            #pragma unroll
            for (int j = 0; j < 4; ++j)
                #pragma unroll
                for (int rg = 0; rg < 4; ++rg) {
                    long m = m0g + i * 16 + lk * 4 + rg;
                    long n = n0g + j * 16 + lrow;
                    float v = acc[i][j][rg];
                    if (GELUF) v = geluf(v);
                    if (HASRES) v += R[(long)z * sR + m * N + n];
                    Cf[m * N + n] = v;
                }
    } else {
        ushortT* Ts = smem + wv * 4096;
        __syncthreads();
        #pragma unroll
        for (int i = 0; i < 4; ++i)
            #pragma unroll
            for (int j = 0; j < 4; ++j)
                #pragma unroll
                for (int rg = 0; rg < 4; ++rg) {
                    int ml = i * 16 + lk * 4 + rg;
                    int nl = j * 16 + lrow;
                    float v = acc[i][j][rg];
                    if (GELUF) v = geluf(v);
                    Ts[nl * 64 + (((ml >> 3) ^ (nl & 7)) << 3) + (ml & 7)] = f2bf(v);
                }
        __syncthreads();
        ushortT* CT = (ushortT*)Cp + (long)z * sC;
        #pragma unroll
        for (int p = 0; p < 8; ++p) {
            int nl = p * 8 + (l >> 3), mc = l & 7;
            uint4 d = *(const uint4*)&Ts[nl * 64 + ((mc ^ (nl & 7)) << 3)];
            *(uint4*)&CT[(long)(n0g + nl) * M + m0g + mc * 8] = d;
        }
    }
}

extern "C" void kernel_launch(void* const* d_in, const int* in_sizes, int n_in,
                              void* d_out, int out_size, void* d_ws, size_t ws_size,
                              hipStream_t stream)
{
    const float* x    = (const float*)d_in[0];
    const float* n1w  = (const float*)d_in[1];
    const float* n1b  = (const float*)d_in[2];
    const float* freqs= (const float*)d_in[3];
    const float* qw   = (const float*)d_in[4];
    const float* ow   = (const float*)d_in[5];
    const float* n2w  = (const float*)d_in[6];
    const float* n2b  = (const float*)d_in[7];
    const float* l1w  = (const float*)d_in[8];
    const float* l2w  = (const float*)d_in[9];
    float* out = (float*)d_out;
    char* wsb  = (char*)d_ws;
    const long MB = 1L << 20;

    ushortT* znT  = (ushortT*)(wsb +   0 * MB);   // 16MB
    ushortT* yT   = (ushortT*)(wsb +  16 * MB);   // 16MB
    ushortT* rotT = (ushortT*)(wsb +  32 * MB);   // 16MB
    ushortT* CfT  = (ushortT*)(wsb +  48 * MB);   // 16MB
    ushortT* zn2T = (ushortT*)(wsb +  64 * MB);   // 16MB
    ushortT* h1T  = (ushortT*)(wsb +  80 * MB);   // 64MB
    float*   cosT = (float*)  (wsb + 144 * MB);
    float*   sinT = cosT + WW * 16;

    rope_tab_k<<<32, 256, 0, stream>>>(freqs, cosT, sinT);

    // norm1: x -> znT (bf16 [w][f])
    normT_k<<<BB * CCH * 16, 1024, 0, stream>>>(x, n1w, n1b, znT);

    // qproj (fp32 weights direct), transposed bf16 out: yT[bc][w][g]
    fgemm_k<false, false, true><<<512, 256, 0, stream>>>(
        qw,  (long)BINS * BINS, CCH,
        znT, (long)WW * BINS,
        yT,  (long)WW * BINS,
        nullptr, 0, BINS, WW, BINS, 4, 8);

    // rope: yT -> rotT (bf16)
    ropeB_k<<<4096, 256, 0, stream>>>(yT, cosT, sinT, rotT);

    // MFMA flash attention -> CfT [bc][w][g]
    mattn_k<<<dim3(8, 256), 256, 0, stream>>>(rotT, yT, CfT);

    // outproj + residual: out = x + ow[c] @ CfT^T
    fgemm_k<true, false, false><<<512, 256, 0, stream>>>(
        ow,  (long)BINS * BINS, CCH,
        CfT, (long)WW * BINS,
        out, (long)BINS * WW,
        x,   (long)BINS * WW, BINS, WW, BINS, 4, 8);

    // norm2: out -> zn2T (bf16 [w][f])
    normT_k<<<BB * CCH * 16, 1024, 0, stream>>>(out, n2w, n2b, zn2T);

    // lin1 + GELU, transposed bf16 out: h1T [w][4096]
    fgemm_k<false, true, true><<<2048, 256, 0, stream>>>(
        l1w,  (long)BINS * EXPF * BINS, CCH,
        zn2T, (long)WW * BINS,
        h1T,  (long)WW * BINS * EXPF,
        nullptr, 0, BINS * EXPF, WW, BINS, 4, 32);

    // lin2 + residual (in-place on out)
    fgemm_k<true, false, false><<<512, 256, 0, stream>>>(
        l2w, (long)BINS * BINS * EXPF, CCH,
        h1T, (long)WW * BINS * EXPF,
        out, (long)BINS * WW,
        out, (long)BINS * WW, BINS, WW, BINS * EXPF, 4, 8);
}